// Round 2
// baseline (1104.645 us; speedup 1.0000x reference)
//
#include <hip/hip_runtime.h>
#include <cstdint>
#include <cmath>

// Problem constants (B=4, S=1024)
#define T_TOK 4096
#define H_DIM 1024
#define QKV_N 3072
#define S_LEN 1024
#define INTER_DIM 2048
#define MAXROWS 9216   // 2*T + 8*127 padding, rounded

typedef unsigned short u16;
using f32x4 = __attribute__((ext_vector_type(4))) float;
using h16x8 = __attribute__((ext_vector_type(8))) _Float16;
using h16x4 = __attribute__((ext_vector_type(4))) _Float16;
using i32x4 = __attribute__((ext_vector_type(4))) int;
using u16x4 = __attribute__((ext_vector_type(4))) u16;

__device__ __forceinline__ float bf2f(u16 u){ return __uint_as_float(((uint32_t)u)<<16); }
__device__ __forceinline__ u16 f2bf(float f){
  uint32_t x = __float_as_uint(f);
  uint32_t r = x + 0x7FFFu + ((x>>16)&1u);
  return (u16)(r>>16);
}
__device__ __forceinline__ f32x4 mfma16(h16x8 a, h16x8 b, f32x4 c){
  return __builtin_amdgcn_mfma_f32_16x16x32_f16(a,b,c,0,0,0);
}
__device__ __forceinline__ float rsqrt_acc(float v){
  float r = rsqrtf(v);
  r = r*(1.5f - 0.5f*v*r*r);
  r = r*(1.5f - 0.5f*v*r*r);
  return r;
}
// dual-dtype scalar input read
__device__ __forceinline__ float ldin(const void* p, size_t i, int is32){
  return is32 ? ((const float*)p)[i] : bf2f(((const u16*)p)[i]);
}

// ---------------- dtype detection: fp32 exponent fields of N(0,1) data ----------------
__global__ void k_detect(const uint32_t* __restrict__ x, int* __restrict__ dflag){
  uint32_t u = x[threadIdx.x];
  int e = (u>>23)&0xFF;
  int ok = (e>=103 && e<=150);            // |f| in [2^-24, 2^23]
  unsigned long long m = __ballot(ok);
  if (threadIdx.x==0) *dflag = (__popcll(m) >= 48) ? 1 : 0;
}

// ---------------- transpose + cast to f16 (qkv_w, o_w) ----------------
__global__ __launch_bounds__(256) void k_transpose_cast(const void* __restrict__ src,
    _Float16* __restrict__ dst, int R, int C, const int* __restrict__ df){
  const int is32 = *df;
  __shared__ _Float16 tile[32][33];
  int tx = threadIdx.x & 31, ty = threadIdx.x >> 5;
  size_t bo = (size_t)blockIdx.z * R * C;
  int c0 = blockIdx.x<<5, r0 = blockIdx.y<<5;
  #pragma unroll
  for (int i=0;i<4;i++){
    int r = ty + i*8;
    tile[r][tx] = (_Float16)ldin(src, bo + (size_t)(r0+r)*C + (c0+tx), is32);
  }
  __syncthreads();
  #pragma unroll
  for (int i=0;i<4;i++){
    int r = ty + i*8;
    dst[bo + (size_t)(c0+r)*R + (r0+tx)] = tile[tx][r];
  }
}

// ---------------- mask all-zero check ----------------
__global__ __launch_bounds__(256) void k_maskchk(const void* __restrict__ m, int* __restrict__ flag,
                                                 const int* __restrict__ df){
  const int is32 = *df;
  int i = (blockIdx.x*256 + threadIdx.x)*4;
  int nz = 0;
  if (is32){
    f32x4 v = *(const f32x4*)&((const float*)m)[i];
    nz = (v[0]!=0.f)||(v[1]!=0.f)||(v[2]!=0.f)||(v[3]!=0.f);
  } else {
    u16x4 v = *(const u16x4*)&((const u16*)m)[i];
    nz = ((v[0]|v[1]|v[2]|v[3]) & 0x7FFF) != 0;
  }
  if (nz) atomicOr(flag, 1);
}

// ---------------- RMSNorm #1: x -> fp32 h ----------------
__global__ __launch_bounds__(256) void k_rms1(const void* __restrict__ x, const void* __restrict__ w,
                                              float* __restrict__ h, const int* __restrict__ df){
  const int is32 = *df;
  int t = blockIdx.x, tid = threadIdx.x;
  size_t base = (size_t)t*H_DIM + tid*4;
  float f[4];
  #pragma unroll
  for (int m=0;m<4;m++) f[m] = ldin(x, base+m, is32);
  float ss = f[0]*f[0] + f[1]*f[1] + f[2]*f[2] + f[3]*f[3];
  #pragma unroll
  for (int off=32; off>0; off>>=1) ss += __shfl_down(ss, off, 64);
  __shared__ float red[4];
  if ((tid & 63) == 0) red[tid>>6] = ss;
  __syncthreads();
  float rstd = rsqrt_acc((red[0]+red[1]+red[2]+red[3]) * (1.0f/H_DIM) + 1e-6f);
  f32x4 o;
  #pragma unroll
  for (int m=0;m<4;m++) o[m] = f[m]*rstd*ldin(w, tid*4+m, is32);
  *(f32x4*)&h[base] = o;
}

// ---------------- high-precision GEMM: fp32 A split to f16 hi/lo, f16 B (exact) ----
// C = A @ Bt^T (+ residual).  EPI 0: C fp32.  EPI 1: C = acc + dual-dtype res.
template<int EPI>
__global__ __launch_bounds__(256) void k_gemm_splitA(const float* __restrict__ A,
    const _Float16* __restrict__ Bt, float* __restrict__ C, const void* __restrict__ res,
    int N, int K, const int* __restrict__ df){
  const int is32 = *df;
  __shared__ __align__(16) _Float16 Ahi[128*32];
  __shared__ __align__(16) _Float16 Alo[128*32];
  __shared__ __align__(16) _Float16 Bs[128*32];
  int tid = threadIdx.x, lane = tid&63, wvx = tid>>6;
  int wr = wvx>>1, wc = wvx&1, quad = lane>>4, lrow = lane&15;
  int m0 = blockIdx.y<<7, n0 = blockIdx.x<<7;
  f32x4 acc[4][4] = {};
  for (int k0=0; k0<K; k0+=32){
    #pragma unroll
    for (int it=0; it<4; it++){
      int ch = it*256 + tid;
      int r = ch>>3, g = ch&7;
      f32x4 v = *(const f32x4*)&A[(size_t)(m0+r)*K + k0 + g*4];
      h16x4 hi, lo;
      #pragma unroll
      for (int q2=0;q2<4;q2++){
        _Float16 hh = (_Float16)v[q2];
        hi[q2] = hh;
        lo[q2] = (_Float16)(v[q2] - (float)hh);
      }
      *(h16x4*)&Ahi[r*32 + g*4] = hi;
      *(h16x4*)&Alo[r*32 + g*4] = lo;
    }
    #pragma unroll
    for (int it=0; it<2; it++){
      int ch = it*256 + tid;
      *(i32x4*)&Bs[ch*8] = *(const i32x4*)&Bt[(size_t)(n0 + (ch>>2))*K + k0 + (ch&3)*8];
    }
    __syncthreads();
    h16x8 ah[4], al[4], bb[4];
    #pragma unroll
    for (int i=0;i<4;i++){
      ah[i] = *(const h16x8*)&Ahi[(wr*64 + i*16 + lrow)*32 + quad*8];
      al[i] = *(const h16x8*)&Alo[(wr*64 + i*16 + lrow)*32 + quad*8];
    }
    #pragma unroll
    for (int j=0;j<4;j++) bb[j] = *(const h16x8*)&Bs[(wc*64 + j*16 + lrow)*32 + quad*8];
    #pragma unroll
    for (int i=0;i<4;i++)
      #pragma unroll
      for (int j=0;j<4;j++){
        acc[i][j] = mfma16(ah[i], bb[j], acc[i][j]);
        acc[i][j] = mfma16(al[i], bb[j], acc[i][j]);
      }
    __syncthreads();
  }
  #pragma unroll
  for (int i=0;i<4;i++)
    #pragma unroll
    for (int j=0;j<4;j++){
      int col = n0 + wc*64 + j*16 + lrow;
      #pragma unroll
      for (int r=0;r<4;r++){
        int row = m0 + wr*64 + i*16 + quad*4 + r;   // C/D: col=lane&15, row=quad*4+reg
        size_t idx = (size_t)row*N + col;
        float v = acc[i][j][r];
        if (EPI==1) v += ldin(res, idx, is32);
        C[idx] = v;
      }
    }
}

// ---------------- flash attention, fp32 qkv in, split-f16 MFMA, fp32 out ----------
__global__ __launch_bounds__(256) void k_attn(const float* __restrict__ qkv, const void* __restrict__ mask,
                                              const int* __restrict__ mflag, float* __restrict__ aout,
                                              const int* __restrict__ df){
  const int is32 = *df;
  __shared__ __align__(16) _Float16 Qhi[2*128*32], Qlo[2*128*32];
  __shared__ __align__(16) _Float16 Khi[2*32*32],  Klo[2*32*32];
  __shared__ __align__(16) _Float16 Vhi[64*32],    Vlo[64*32];
  __shared__ __align__(16) _Float16 Phi[128*32],   Plo[128*32];
  int qt = blockIdx.x, bh = blockIdx.y;
  int b = bh>>4, h = bh&15;
  int tid = threadIdx.x, lane = tid&63, wvx = tid>>6, quad = lane>>4, lrow = lane&15;
  size_t tok0 = (size_t)b*S_LEN;
  int q0 = qt<<7;
  #pragma unroll
  for (int it=0; it<8; it++){
    int idx = it*256 + tid;
    int r = idx>>4, g = idx&15;
    int d0 = g*4, p = g>>3;
    f32x4 v = *(const f32x4*)&qkv[(tok0 + q0 + r)*QKV_N + h*64 + d0];
    h16x4 hi, lo;
    #pragma unroll
    for (int m=0;m<4;m++){ _Float16 hh=(_Float16)v[m]; hi[m]=hh; lo[m]=(_Float16)(v[m]-(float)hh); }
    *(h16x4*)&Qhi[(p*128 + r)*32 + (d0&31)] = hi;
    *(h16x4*)&Qlo[(p*128 + r)*32 + (d0&31)] = lo;
  }
  int useMask = *mflag;
  float mrun[2][4], lrun[2][4];
  f32x4 oacc[2][4] = {};
  #pragma unroll
  for (int i=0;i<2;i++)
    #pragma unroll
    for (int r=0;r<4;r++){ mrun[i][r] = -INFINITY; lrun[i][r] = 0.f; }

  for (int kt=0; kt<32; kt++){
    int key0 = kt*32;
    __syncthreads();
    #pragma unroll
    for (int it=0; it<2; it++){
      int idx = it*256 + tid;
      int key = idx>>4, g = idx&15;
      int d0 = g*4, p = g>>3;
      f32x4 v = *(const f32x4*)&qkv[(tok0 + key0 + key)*QKV_N + 1024 + h*64 + d0];
      h16x4 hi, lo;
      #pragma unroll
      for (int m=0;m<4;m++){ _Float16 hh=(_Float16)v[m]; hi[m]=hh; lo[m]=(_Float16)(v[m]-(float)hh); }
      *(h16x4*)&Khi[(p*32 + key)*32 + (d0&31)] = hi;
      *(h16x4*)&Klo[(p*32 + key)*32 + (d0&31)] = lo;
    }
    #pragma unroll
    for (int it=0; it<2; it++){
      int idx = it*256 + tid;
      int key = idx & 31, dg = idx >> 5;
      int d0 = dg*4;
      f32x4 v = *(const f32x4*)&qkv[(tok0 + key0 + key)*QKV_N + 2048 + h*64 + d0];
      #pragma unroll
      for (int m=0;m<4;m++){
        _Float16 hh = (_Float16)v[m];
        Vhi[(d0+m)*32 + key] = hh;
        Vlo[(d0+m)*32 + key] = (_Float16)(v[m]-(float)hh);
      }
    }
    __syncthreads();
    // S = Q K^T (3-product split)
    f32x4 sacc[2][2] = {};
    #pragma unroll
    for (int p=0;p<2;p++){
      h16x8 qh[2], ql[2], kh[2], kl[2];
      #pragma unroll
      for (int i=0;i<2;i++){
        qh[i] = *(const h16x8*)&Qhi[(p*128 + wvx*32 + i*16 + lrow)*32 + quad*8];
        ql[i] = *(const h16x8*)&Qlo[(p*128 + wvx*32 + i*16 + lrow)*32 + quad*8];
      }
      #pragma unroll
      for (int j=0;j<2;j++){
        kh[j] = *(const h16x8*)&Khi[(p*32 + j*16 + lrow)*32 + quad*8];
        kl[j] = *(const h16x8*)&Klo[(p*32 + j*16 + lrow)*32 + quad*8];
      }
      #pragma unroll
      for (int i=0;i<2;i++)
        #pragma unroll
        for (int j=0;j<2;j++){
          sacc[i][j] = mfma16(qh[i], kh[j], sacc[i][j]);
          sacc[i][j] = mfma16(qh[i], kl[j], sacc[i][j]);
          sacc[i][j] = mfma16(ql[i], kh[j], sacc[i][j]);
        }
    }
    // online softmax per row
    #pragma unroll
    for (int i=0;i<2;i++){
      #pragma unroll
      for (int r=0;r<4;r++){
        int qrow = q0 + wvx*32 + i*16 + quad*4 + r;
        #pragma unroll
        for (int j=0;j<2;j++){
          float s = sacc[i][j][r] * 0.125f;
          if (useMask) s += ldin(mask, (size_t)qrow*S_LEN + key0 + j*16 + lrow, is32);
          sacc[i][j][r] = s;
        }
        float mx = fmaxf(sacc[i][0][r], sacc[i][1][r]);
        #pragma unroll
        for (int mm=1; mm<=8; mm<<=1) mx = fmaxf(mx, __shfl_xor(mx, mm, 64));
        float mnew = fmaxf(mrun[i][r], mx);
        float alpha = __expf(mrun[i][r] - mnew);
        float ps = 0.f;
        #pragma unroll
        for (int j=0;j<2;j++){
          float p = __expf(sacc[i][j][r] - mnew);
          sacc[i][j][r] = p;
          ps += p;
        }
        #pragma unroll
        for (int mm=1; mm<=8; mm<<=1) ps += __shfl_xor(ps, mm, 64);
        lrun[i][r] = lrun[i][r]*alpha + ps;
        mrun[i][r] = mnew;
        #pragma unroll
        for (int j=0;j<4;j++) oacc[i][j][r] *= alpha;
        int prow = wvx*32 + i*16 + quad*4 + r;
        #pragma unroll
        for (int j=0;j<2;j++){
          int key = j*16 + lrow;
          float pv = sacc[i][j][r];
          _Float16 ph = (_Float16)pv;
          Phi[prow*32 + key] = ph;
          Plo[prow*32 + key] = (_Float16)(pv - (float)ph);
        }
      }
    }
    __syncthreads();   // defensive: make Phi/Plo writes visible before fragment reads
    // O += P V (3-product split)
    {
      h16x8 pf[2], pl[2], vh[4], vl[4];
      #pragma unroll
      for (int i=0;i<2;i++){
        pf[i] = *(const h16x8*)&Phi[(wvx*32 + i*16 + lrow)*32 + quad*8];
        pl[i] = *(const h16x8*)&Plo[(wvx*32 + i*16 + lrow)*32 + quad*8];
      }
      #pragma unroll
      for (int j=0;j<4;j++){
        vh[j] = *(const h16x8*)&Vhi[(j*16 + lrow)*32 + quad*8];
        vl[j] = *(const h16x8*)&Vlo[(j*16 + lrow)*32 + quad*8];
      }
      #pragma unroll
      for (int i=0;i<2;i++)
        #pragma unroll
        for (int j=0;j<4;j++){
          oacc[i][j] = mfma16(pf[i], vh[j], oacc[i][j]);
          oacc[i][j] = mfma16(pf[i], vl[j], oacc[i][j]);
          oacc[i][j] = mfma16(pl[i], vh[j], oacc[i][j]);
        }
    }
  }
  #pragma unroll
  for (int i=0;i<2;i++)
    #pragma unroll
    for (int j=0;j<4;j++)
      #pragma unroll
      for (int r=0;r<4;r++){
        int row = q0 + wvx*32 + i*16 + quad*4 + r;
        int col = h*64 + j*16 + lrow;
        aout[(tok0 + row)*H_DIM + col] = oacc[i][j][r] / lrun[i][r];
      }
}

// ---------------- RMSNorm #2 + router (fp32 logits, top-2) ----------------
__global__ __launch_bounds__(256) void k_rms2_router(const float* __restrict__ x1, const void* __restrict__ w,
    const void* __restrict__ rw, _Float16* __restrict__ h2,
    int* __restrict__ tok_e, float* __restrict__ tok_w, int* __restrict__ counts,
    const int* __restrict__ df){
  const int is32 = *df;
  int t = blockIdx.x, tid = threadIdx.x;
  f32x4 v = *(const f32x4*)&x1[(size_t)t*H_DIM + tid*4];
  float ss = v[0]*v[0]+v[1]*v[1]+v[2]*v[2]+v[3]*v[3];
  #pragma unroll
  for (int off=32; off>0; off>>=1) ss += __shfl_down(ss, off, 64);
  __shared__ float red[4];
  __shared__ float lgs[32];
  if ((tid&63)==0) red[tid>>6] = ss;
  __syncthreads();
  float rstd = rsqrt_acc((red[0]+red[1]+red[2]+red[3])*(1.0f/H_DIM) + 1e-6f);
  float hv[4];
  h16x4 hst;
  #pragma unroll
  for (int m=0;m<4;m++){ hv[m] = v[m]*rstd*ldin(w, tid*4+m, is32); hst[m] = (_Float16)hv[m]; }
  *(h16x4*)&h2[(size_t)t*H_DIM + tid*4] = hst;
  float part[8] = {0,0,0,0,0,0,0,0};
  #pragma unroll
  for (int m=0;m<4;m++){
    size_t c = (size_t)(tid*4 + m)*8;
    #pragma unroll
    for (int e=0;e<8;e++) part[e] += hv[m]*ldin(rw, c+e, is32);
  }
  #pragma unroll
  for (int e=0;e<8;e++){
    #pragma unroll
    for (int off=32; off>0; off>>=1) part[e] += __shfl_down(part[e], off, 64);
  }
  if ((tid&63)==0){
    #pragma unroll
    for (int e=0;e<8;e++) lgs[(tid>>6)*8 + e] = part[e];
  }
  __syncthreads();
  if (tid==0){
    float lg[8];
    #pragma unroll
    for (int e=0;e<8;e++) lg[e] = lgs[e] + lgs[8+e] + lgs[16+e] + lgs[24+e];
    int e0 = 0;
    #pragma unroll
    for (int e=1;e<8;e++) if (lg[e] > lg[e0]) e0 = e;
    int e1 = (e0==0) ? 1 : 0;
    #pragma unroll
    for (int e=0;e<8;e++) if (e != e0 && lg[e] > lg[e1]) e1 = e;
    float d = expf(lg[e1] - lg[e0]);
    float w0 = 1.0f/(1.0f + d);
    float w1 = d * w0;
    tok_e[t*2] = e0; tok_e[t*2+1] = e1;
    tok_w[t*2] = w0; tok_w[t*2+1] = w1;
    atomicAdd(&counts[e0], 1);
    atomicAdd(&counts[e1], 1);
  }
}

// ---------------- expert offsets (padded prefix) ----------------
__global__ void k_offsets(const int* __restrict__ counts, int* __restrict__ offs, int* __restrict__ fillpos){
  if (threadIdx.x == 0 && blockIdx.x == 0){
    int o = 0;
    for (int e=0;e<8;e++){
      offs[e] = o; fillpos[e] = o;
      o += (counts[e] + 127) & ~127;
    }
    offs[8] = o;
  }
}

// ---------------- fill compact token lists ----------------
__global__ __launch_bounds__(256) void k_fill(const int* __restrict__ tok_e, const float* __restrict__ tok_w,
    int* __restrict__ fillpos, int* __restrict__ list_ts, float* __restrict__ list_w){
  int t = blockIdx.x*256 + threadIdx.x;
  if (t >= T_TOK) return;
  #pragma unroll
  for (int s=0;s<2;s++){
    int e = tok_e[t*2+s];
    int p = atomicAdd(&fillpos[e], 1);
    list_ts[p] = t*2 + s;
    list_w[p] = tok_w[t*2+s];
  }
}

// ---------------- gathered gate+up GEMM fused with SiLU; B read natively [K][N] ----
__global__ __launch_bounds__(256) void k_gemm_gu(const _Float16* __restrict__ h2, const void* __restrict__ guw,
    _Float16* __restrict__ act, const int* __restrict__ list_ts,
    const int* __restrict__ counts, const int* __restrict__ offs, const int* __restrict__ df){
  const int is32 = *df;
  int m0 = blockIdx.y<<7;
  if (m0 >= offs[8]) return;
  int e = 0;
  while (m0 >= offs[e+1]) e++;
  int base = offs[e], cnt = counts[e];
  if (m0 >= base + cnt) return;
  __shared__ __align__(16) _Float16 As[128*32], Bg[64*32], Bu[64*32];
  __shared__ int rowtok[128];
  int tid = threadIdx.x;
  if (tid < 128){
    int mc = min(m0 + tid, base + cnt - 1);
    rowtok[tid] = list_ts[mc] >> 1;
  }
  __syncthreads();
  int lane = tid&63, wvx = tid>>6, wr = wvx>>1, wc = wvx&1, quad = lane>>4, lrow = lane&15;
  int n0 = blockIdx.x<<6;
  size_t ebase = (size_t)e*H_DIM*4096;
  f32x4 ag[4][2] = {}, au[4][2] = {};
  for (int k0=0; k0<1024; k0+=32){
    #pragma unroll
    for (int it=0; it<2; it++){
      int ch = it*256 + tid;
      int r = ch>>2, c = ch&3;
      *(i32x4*)&As[ch*8] = *(const i32x4*)&h2[(size_t)rowtok[r]*H_DIM + k0 + c*8];
    }
    // B staging from native [k][n]: thread -> (k=tid>>3, 8 cols at g*8)
    {
      int k = tid>>3, g = tid&7;
      size_t rowb = ebase + (size_t)(k0+k)*4096;
      _Float16 tg[8], tu[8];
      if (is32){
        const float* gf = (const float*)guw;
        f32x4 a0 = *(const f32x4*)&gf[rowb + n0 + g*8];
        f32x4 a1 = *(const f32x4*)&gf[rowb + n0 + g*8 + 4];
        f32x4 b0 = *(const f32x4*)&gf[rowb + 2048 + n0 + g*8];
        f32x4 b1 = *(const f32x4*)&gf[rowb + 2048 + n0 + g*8 + 4];
        #pragma unroll
        for (int i=0;i<4;i++){ tg[i]=(_Float16)a0[i]; tg[4+i]=(_Float16)a1[i];
                               tu[i]=(_Float16)b0[i]; tu[4+i]=(_Float16)b1[i]; }
      } else {
        const u16* gb = (const u16*)guw;
        u16x4 a0 = *(const u16x4*)&gb[rowb + n0 + g*8];
        u16x4 a1 = *(const u16x4*)&gb[rowb + n0 + g*8 + 4];
        u16x4 b0 = *(const u16x4*)&gb[rowb + 2048 + n0 + g*8];
        u16x4 b1 = *(const u16x4*)&gb[rowb + 2048 + n0 + g*8 + 4];
        #pragma unroll
        for (int i=0;i<4;i++){ tg[i]=(_Float16)bf2f(a0[i]); tg[4+i]=(_Float16)bf2f(a1[i]);
                               tu[i]=(_Float16)bf2f(b0[i]); tu[4+i]=(_Float16)bf2f(b1[i]); }
      }
      #pragma unroll
      for (int i=0;i<8;i++){
        int n = g*8 + i;
        int sk = k ^ ((n&3)*8);          // XOR-octet swizzle keeps frag reads b128-aligned
        Bg[n*32 + sk] = tg[i];
        Bu[n*32 + sk] = tu[i];
      }
    }
    __syncthreads();
    h16x8 a[4], bg[2], bu[2];
    #pragma unroll
    for (int i=0;i<4;i++) a[i] = *(const h16x8*)&As[(wr*64 + i*16 + lrow)*32 + quad*8];
    #pragma unroll
    for (int j=0;j<2;j++){
      int n = wc*32 + j*16 + lrow;
      int oct = (quad ^ (n&3))*8;
      bg[j] = *(const h16x8*)&Bg[n*32 + oct];
      bu[j] = *(const h16x8*)&Bu[n*32 + oct];
    }
    #pragma unroll
    for (int i=0;i<4;i++)
      #pragma unroll
      for (int j=0;j<2;j++){
        ag[i][j] = mfma16(a[i], bg[j], ag[i][j]);
        au[i][j] = mfma16(a[i], bu[j], au[i][j]);
      }
    __syncthreads();
  }
  #pragma unroll
  for (int i=0;i<4;i++)
    #pragma unroll
    for (int j=0;j<2;j++)
      #pragma unroll
      for (int r=0;r<4;r++){
        int row = m0 + wr*64 + i*16 + quad*4 + r;
        int col = n0 + wc*32 + j*16 + lrow;
        float g = ag[i][j][r], u = au[i][j][r];
        float sv = g / (1.0f + __expf(-g));
        act[(size_t)row*INTER_DIM + col] = (_Float16)(sv * u);
      }
}

// ---------------- down GEMM (B native [K][N]), scatter w*val into (token,slot) ----
__global__ __launch_bounds__(256) void k_gemm_down(const _Float16* __restrict__ act, const void* __restrict__ dw,
    _Float16* __restrict__ slotbuf, const int* __restrict__ list_ts, const float* __restrict__ list_w,
    const int* __restrict__ counts, const int* __restrict__ offs, const int* __restrict__ df){
  const int is32 = *df;
  int m0 = blockIdx.y<<7;
  if (m0 >= offs[8]) return;
  int e = 0;
  while (m0 >= offs[e+1]) e++;
  int base = offs[e], cnt = counts[e];
  if (m0 >= base + cnt) return;
  __shared__ __align__(16) _Float16 As[128*32], Bs[128*32];
  int tid = threadIdx.x, lane = tid&63, wvx = tid>>6;
  int wr = wvx>>1, wc = wvx&1, quad = lane>>4, lrow = lane&15;
  int n0 = blockIdx.x<<7;
  size_t ebase = (size_t)e*INTER_DIM*H_DIM;
  f32x4 acc[4][4] = {};
  for (int k0=0; k0<2048; k0+=32){
    #pragma unroll
    for (int it=0; it<2; it++){
      int ch = it*256 + tid;
      int r = ch>>2, c = ch&3;
      *(i32x4*)&As[ch*8] = *(const i32x4*)&act[(size_t)(m0+r)*INTER_DIM + k0 + c*8];
    }
    // B staging from native [k][n]: 2 passes, thread -> (k = kk*16 + tid>>4, 8 cols)
    #pragma unroll
    for (int kk=0; kk<2; kk++){
      int k = kk*16 + (tid>>4), g = tid&15;
      size_t rowb = ebase + (size_t)(k0+k)*H_DIM;
      _Float16 tb[8];
      if (is32){
        const float* bf = (const float*)dw;
        f32x4 a0 = *(const f32x4*)&bf[rowb + n0 + g*8];
        f32x4 a1 = *(const f32x4*)&bf[rowb + n0 + g*8 + 4];
        #pragma unroll
        for (int i=0;i<4;i++){ tb[i]=(_Float16)a0[i]; tb[4+i]=(_Float16)a1[i]; }
      } else {
        const u16* bb = (const u16*)dw;
        u16x4 a0 = *(const u16x4*)&bb[rowb + n0 + g*8];
        u16x4 a1 = *(const u16x4*)&bb[rowb + n0 + g*8 + 4];
        #pragma unroll
        for (int i=0;i<4;i++){ tb[i]=(_Float16)bf2f(a0[i]); tb[4+i]=(_Float16)bf2f(a1[i]); }
      }
      #pragma unroll
      for (int i=0;i<8;i++){
        int n = g*8 + i;
        Bs[n*32 + (k ^ ((n&3)*8))] = tb[i];
      }
    }
    __syncthreads();
    h16x8 a[4], b[4];
    #pragma unroll
    for (int i=0;i<4;i++) a[i] = *(const h16x8*)&As[(wr*64 + i*16 + lrow)*32 + quad*8];
    #pragma unroll
    for (int j=0;j<4;j++){
      int n = wc*64 + j*16 + lrow;
      b[j] = *(const h16x8*)&Bs[n*32 + ((quad ^ (n&3))*8)];
    }
    #pragma unroll
    for (int i=0;i<4;i++)
      #pragma unroll
      for (int j=0;j<4;j++)
        acc[i][j] = mfma16(a[i], b[j], acc[i][j]);
    __syncthreads();
  }
  #pragma unroll
  for (int i=0;i<4;i++)
    #pragma unroll
    for (int r=0;r<4;r++){
      int m = m0 + wr*64 + i*16 + quad*4 + r;
      if (m < base + cnt){
        int ts = list_ts[m];
        float wgt = list_w[m];
        #pragma unroll
        for (int j=0;j<4;j++){
          int col = n0 + wc*64 + j*16 + lrow;
          slotbuf[(size_t)ts*H_DIM + col] = (_Float16)(wgt * acc[i][j][r]);
        }
      }
    }
}

// ---------------- final residual add -> dual-dtype out ----------------
__global__ __launch_bounds__(256) void k_final(const float* __restrict__ x1, const _Float16* __restrict__ slot,
                                               void* __restrict__ outv, const int* __restrict__ df){
  const int is32 = *df;
  int i4 = (blockIdx.x*256 + threadIdx.x)*4;
  int t = i4 >> 10, c = i4 & 1023;
  f32x4 a = *(const f32x4*)&x1[i4];
  h16x4 s0 = *(const h16x4*)&slot[(size_t)(t*2)*H_DIM + c];
  h16x4 s1 = *(const h16x4*)&slot[(size_t)(t*2+1)*H_DIM + c];
  if (is32){
    f32x4 o;
    #pragma unroll
    for (int m=0;m<4;m++) o[m] = a[m] + (float)s0[m] + (float)s1[m];
    *(f32x4*)&((float*)outv)[i4] = o;
  } else {
    u16x4 o;
    #pragma unroll
    for (int m=0;m<4;m++) o[m] = f2bf(a[m] + (float)s0[m] + (float)s1[m]);
    *(u16x4*)&((u16*)outv)[i4] = o;
  }
}

extern "C" void kernel_launch(void* const* d_in, const int* in_sizes, int n_in,
                              void* d_out, int out_size, void* d_ws, size_t ws_size,
                              hipStream_t stream){
  (void)in_sizes; (void)n_in; (void)out_size; (void)ws_size;
  const void* x    = d_in[0];
  const void* mask = d_in[1];
  const void* ln1  = d_in[2];
  const void* ln2  = d_in[3];
  const void* qkvw = d_in[4];
  const void* ow   = d_in[5];
  const void* rw   = d_in[6];
  const void* guw  = d_in[7];
  const void* dww  = d_in[8];

  char* ws = (char*)d_ws;
  size_t off = 0;
  auto alloc = [&](size_t b)->void*{ void* p = ws + off; off = (off + b + 255) & ~(size_t)255; return p; };
  int* meta            = (int*)alloc(32*sizeof(int));
  _Float16* qkv_wt     = (_Float16*)alloc((size_t)3072*1024*2);
  _Float16* o_wt       = (_Float16*)alloc((size_t)1024*1024*2);
  float* hbuf          = (float*)alloc((size_t)4096*1024*4);    // h, then attn-out
  float* qkvbuf        = (float*)alloc((size_t)4096*3072*4);    // qkv fp32; later h2+act
  float* x1            = (float*)alloc((size_t)4096*1024*4);
  _Float16* slotbuf    = (_Float16*)alloc((size_t)4096*2*1024*2);
  int* list_ts         = (int*)alloc(MAXROWS*4);
  float* list_w        = (float*)alloc(MAXROWS*4);
  int* tok_e           = (int*)alloc((size_t)4096*2*4);
  float* tok_w         = (float*)alloc((size_t)4096*2*4);
  // total ~105 MB

  int* counts = meta;
  int* offs   = meta + 8;
  int* fillpos= meta + 17;
  int* flag   = meta + 25;
  int* dflag  = meta + 26;
  _Float16* h2  = (_Float16*)qkvbuf;                                // 8 MB
  _Float16* act = (_Float16*)((char*)qkvbuf + (size_t)4096*1024*2); // 37.75 MB, fits in qkvbuf

  hipMemsetAsync(meta, 0, 32*sizeof(int), stream);
  k_detect<<<dim3(1), dim3(64), 0, stream>>>((const uint32_t*)x, dflag);
  k_transpose_cast<<<dim3(3072/32, 1024/32, 1), 256, 0, stream>>>(qkvw, qkv_wt, 1024, 3072, dflag);
  k_transpose_cast<<<dim3(1024/32, 1024/32, 1), 256, 0, stream>>>(ow, o_wt, 1024, 1024, dflag);
  k_maskchk<<<dim3(1024), 256, 0, stream>>>(mask, flag, dflag);
  k_rms1<<<dim3(4096), 256, 0, stream>>>(x, ln1, hbuf, dflag);
  k_gemm_splitA<0><<<dim3(24, 32), 256, 0, stream>>>(hbuf, qkv_wt, qkvbuf, nullptr, 3072, 1024, dflag);
  k_attn<<<dim3(8, 64), 256, 0, stream>>>(qkvbuf, mask, flag, hbuf, dflag);
  k_gemm_splitA<1><<<dim3(8, 32), 256, 0, stream>>>(hbuf, o_wt, x1, x, 1024, 1024, dflag);
  k_rms2_router<<<dim3(4096), 256, 0, stream>>>(x1, ln2, rw, h2, tok_e, tok_w, counts, dflag);
  k_offsets<<<dim3(1), dim3(64), 0, stream>>>(counts, offs, fillpos);
  k_fill<<<dim3(16), 256, 0, stream>>>(tok_e, tok_w, fillpos, list_ts, list_w);
  k_gemm_gu<<<dim3(32, 72), 256, 0, stream>>>(h2, guw, act, list_ts, counts, offs, dflag);
  k_gemm_down<<<dim3(8, 72), 256, 0, stream>>>(act, dww, slotbuf, list_ts, list_w, counts, offs, dflag);
  k_final<<<dim3(4096), 256, 0, stream>>>(x1, slotbuf, d_out, dflag);
}

// Round 3
// 965.597 us; speedup vs baseline: 1.1440x; 1.1440x over previous
//
#include <hip/hip_runtime.h>
#include <cstdint>
#include <cmath>

// Problem constants (B=4, S=1024)
#define T_TOK 4096
#define H_DIM 1024
#define QKV_N 3072
#define S_LEN 1024
#define INTER_DIM 2048
#define MAXROWS 9216   // 2*T + 8*127 padding, rounded

typedef unsigned short u16;
using f32x4 = __attribute__((ext_vector_type(4))) float;
using h16x8 = __attribute__((ext_vector_type(8))) _Float16;
using h16x4 = __attribute__((ext_vector_type(4))) _Float16;
using i32x4 = __attribute__((ext_vector_type(4))) int;
using u16x4 = __attribute__((ext_vector_type(4))) u16;

__device__ __forceinline__ float bf2f(u16 u){ return __uint_as_float(((uint32_t)u)<<16); }
__device__ __forceinline__ u16 f2bf(float f){
  uint32_t x = __float_as_uint(f);
  uint32_t r = x + 0x7FFFu + ((x>>16)&1u);
  return (u16)(r>>16);
}
__device__ __forceinline__ f32x4 mfma16(h16x8 a, h16x8 b, f32x4 c){
  return __builtin_amdgcn_mfma_f32_16x16x32_f16(a,b,c,0,0,0);
}
__device__ __forceinline__ float rsqrt_acc(float v){
  float r = rsqrtf(v);
  r = r*(1.5f - 0.5f*v*r*r);
  r = r*(1.5f - 0.5f*v*r*r);
  return r;
}
// dual-dtype scalar input read
__device__ __forceinline__ float ldin(const void* p, size_t i, int is32){
  return is32 ? ((const float*)p)[i] : bf2f(((const u16*)p)[i]);
}
// swizzled k-slot for stride-40 B tiles: mixes lane's n-octet into k-octet
__device__ __forceinline__ int kslot_sw(int k, int noct){
  return (k&7) | (((k>>3) ^ (noct&3))<<3);
}

// ---------------- dtype detection: fp32 exponent fields of N(0,1) data ----------------
__global__ void k_detect(const uint32_t* __restrict__ x, int* __restrict__ dflag){
  uint32_t u = x[threadIdx.x];
  int e = (u>>23)&0xFF;
  int ok = (e>=103 && e<=150);            // |f| in [2^-24, 2^23]
  unsigned long long m = __ballot(ok);
  if (threadIdx.x==0) *dflag = (__popcll(m) >= 48) ? 1 : 0;
}

// ---------------- transpose + cast to f16 (qkv_w, o_w) ----------------
__global__ __launch_bounds__(256) void k_transpose_cast(const void* __restrict__ src,
    _Float16* __restrict__ dst, int R, int C, const int* __restrict__ df){
  const int is32 = *df;
  __shared__ _Float16 tile[32][33];
  int tx = threadIdx.x & 31, ty = threadIdx.x >> 5;
  size_t bo = (size_t)blockIdx.z * R * C;
  int c0 = blockIdx.x<<5, r0 = blockIdx.y<<5;
  #pragma unroll
  for (int i=0;i<4;i++){
    int r = ty + i*8;
    tile[r][tx] = (_Float16)ldin(src, bo + (size_t)(r0+r)*C + (c0+tx), is32);
  }
  __syncthreads();
  #pragma unroll
  for (int i=0;i<4;i++){
    int r = ty + i*8;
    dst[bo + (size_t)(c0+r)*R + (r0+tx)] = tile[tx][r];
  }
}

// ---------------- mask all-zero check ----------------
__global__ __launch_bounds__(256) void k_maskchk(const void* __restrict__ m, int* __restrict__ flag,
                                                 const int* __restrict__ df){
  const int is32 = *df;
  int i = (blockIdx.x*256 + threadIdx.x)*4;
  int nz = 0;
  if (is32){
    f32x4 v = *(const f32x4*)&((const float*)m)[i];
    nz = (v[0]!=0.f)||(v[1]!=0.f)||(v[2]!=0.f)||(v[3]!=0.f);
  } else {
    u16x4 v = *(const u16x4*)&((const u16*)m)[i];
    nz = ((v[0]|v[1]|v[2]|v[3]) & 0x7FFF) != 0;
  }
  if (nz) atomicOr(flag, 1);
}

// ---------------- RMSNorm #1: x -> fp32 h ----------------
__global__ __launch_bounds__(256) void k_rms1(const void* __restrict__ x, const void* __restrict__ w,
                                              float* __restrict__ h, const int* __restrict__ df){
  const int is32 = *df;
  int t = blockIdx.x, tid = threadIdx.x;
  size_t base = (size_t)t*H_DIM + tid*4;
  float f[4];
  #pragma unroll
  for (int m=0;m<4;m++) f[m] = ldin(x, base+m, is32);
  float ss = f[0]*f[0] + f[1]*f[1] + f[2]*f[2] + f[3]*f[3];
  #pragma unroll
  for (int off=32; off>0; off>>=1) ss += __shfl_down(ss, off, 64);
  __shared__ float red[4];
  if ((tid & 63) == 0) red[tid>>6] = ss;
  __syncthreads();
  float rstd = rsqrt_acc((red[0]+red[1]+red[2]+red[3]) * (1.0f/H_DIM) + 1e-6f);
  f32x4 o;
  #pragma unroll
  for (int m=0;m<4;m++) o[m] = f[m]*rstd*ldin(w, tid*4+m, is32);
  *(f32x4*)&h[base] = o;
}

// ---------------- high-precision GEMM: fp32 A split to f16 hi/lo, f16 B (exact) ----
// C = A @ Bt^T (+ residual).  EPI 0: C fp32.  EPI 1: C = acc + dual-dtype res.
template<int EPI>
__global__ __launch_bounds__(256) void k_gemm_splitA(const float* __restrict__ A,
    const _Float16* __restrict__ Bt, float* __restrict__ C, const void* __restrict__ res,
    int N, int K, const int* __restrict__ df){
  const int is32 = *df;
  __shared__ __align__(16) _Float16 Ahi[128*32];
  __shared__ __align__(16) _Float16 Alo[128*32];
  __shared__ __align__(16) _Float16 Bs[128*32];
  int tid = threadIdx.x, lane = tid&63, wvx = tid>>6;
  int wr = wvx>>1, wc = wvx&1, quad = lane>>4, lrow = lane&15;
  int m0 = blockIdx.y<<7, n0 = blockIdx.x<<7;
  f32x4 acc[4][4] = {};
  for (int k0=0; k0<K; k0+=32){
    #pragma unroll
    for (int it=0; it<4; it++){
      int ch = it*256 + tid;
      int r = ch>>3, g = ch&7;
      f32x4 v = *(const f32x4*)&A[(size_t)(m0+r)*K + k0 + g*4];
      h16x4 hi, lo;
      #pragma unroll
      for (int q2=0;q2<4;q2++){
        _Float16 hh = (_Float16)v[q2];
        hi[q2] = hh;
        lo[q2] = (_Float16)(v[q2] - (float)hh);
      }
      *(h16x4*)&Ahi[r*32 + g*4] = hi;
      *(h16x4*)&Alo[r*32 + g*4] = lo;
    }
    #pragma unroll
    for (int it=0; it<2; it++){
      int ch = it*256 + tid;
      *(i32x4*)&Bs[ch*8] = *(const i32x4*)&Bt[(size_t)(n0 + (ch>>2))*K + k0 + (ch&3)*8];
    }
    __syncthreads();
    h16x8 ah[4], al[4], bb[4];
    #pragma unroll
    for (int i=0;i<4;i++){
      ah[i] = *(const h16x8*)&Ahi[(wr*64 + i*16 + lrow)*32 + quad*8];
      al[i] = *(const h16x8*)&Alo[(wr*64 + i*16 + lrow)*32 + quad*8];
    }
    #pragma unroll
    for (int j=0;j<4;j++) bb[j] = *(const h16x8*)&Bs[(wc*64 + j*16 + lrow)*32 + quad*8];
    #pragma unroll
    for (int i=0;i<4;i++)
      #pragma unroll
      for (int j=0;j<4;j++){
        acc[i][j] = mfma16(ah[i], bb[j], acc[i][j]);
        acc[i][j] = mfma16(al[i], bb[j], acc[i][j]);
      }
    __syncthreads();
  }
  #pragma unroll
  for (int i=0;i<4;i++)
    #pragma unroll
    for (int j=0;j<4;j++){
      int col = n0 + wc*64 + j*16 + lrow;
      #pragma unroll
      for (int r=0;r<4;r++){
        int row = m0 + wr*64 + i*16 + quad*4 + r;   // C/D: col=lane&15, row=quad*4+reg
        size_t idx = (size_t)row*N + col;
        float v = acc[i][j][r];
        if (EPI==1) v += ldin(res, idx, is32);
        C[idx] = v;
      }
    }
}

// ---------------- flash attention, fp32 qkv in, split-f16 MFMA, fp32 out ----------
__global__ __launch_bounds__(256) void k_attn(const float* __restrict__ qkv, const void* __restrict__ mask,
                                              const int* __restrict__ mflag, float* __restrict__ aout,
                                              const int* __restrict__ df){
  const int is32 = *df;
  __shared__ __align__(16) _Float16 Qhi[2*128*32], Qlo[2*128*32];
  __shared__ __align__(16) _Float16 Khi[2*32*32],  Klo[2*32*32];
  __shared__ __align__(16) _Float16 Vhi[64*32],    Vlo[64*32];
  __shared__ __align__(16) _Float16 Phi[128*32],   Plo[128*32];
  int qt = blockIdx.x, bh = blockIdx.y;
  int b = bh>>4, h = bh&15;
  int tid = threadIdx.x, lane = tid&63, wvx = tid>>6, quad = lane>>4, lrow = lane&15;
  size_t tok0 = (size_t)b*S_LEN;
  int q0 = qt<<7;
  #pragma unroll
  for (int it=0; it<8; it++){
    int idx = it*256 + tid;
    int r = idx>>4, g = idx&15;
    int d0 = g*4, p = g>>3;
    f32x4 v = *(const f32x4*)&qkv[(tok0 + q0 + r)*QKV_N + h*64 + d0];
    h16x4 hi, lo;
    #pragma unroll
    for (int m=0;m<4;m++){ _Float16 hh=(_Float16)v[m]; hi[m]=hh; lo[m]=(_Float16)(v[m]-(float)hh); }
    *(h16x4*)&Qhi[(p*128 + r)*32 + (d0&31)] = hi;
    *(h16x4*)&Qlo[(p*128 + r)*32 + (d0&31)] = lo;
  }
  int useMask = *mflag;
  float mrun[2][4], lrun[2][4];
  f32x4 oacc[2][4] = {};
  #pragma unroll
  for (int i=0;i<2;i++)
    #pragma unroll
    for (int r=0;r<4;r++){ mrun[i][r] = -INFINITY; lrun[i][r] = 0.f; }

  for (int kt=0; kt<32; kt++){
    int key0 = kt*32;
    __syncthreads();
    #pragma unroll
    for (int it=0; it<2; it++){
      int idx = it*256 + tid;
      int key = idx>>4, g = idx&15;
      int d0 = g*4, p = g>>3;
      f32x4 v = *(const f32x4*)&qkv[(tok0 + key0 + key)*QKV_N + 1024 + h*64 + d0];
      h16x4 hi, lo;
      #pragma unroll
      for (int m=0;m<4;m++){ _Float16 hh=(_Float16)v[m]; hi[m]=hh; lo[m]=(_Float16)(v[m]-(float)hh); }
      *(h16x4*)&Khi[(p*32 + key)*32 + (d0&31)] = hi;
      *(h16x4*)&Klo[(p*32 + key)*32 + (d0&31)] = lo;
    }
    #pragma unroll
    for (int it=0; it<2; it++){
      int idx = it*256 + tid;
      int key = idx & 31, dg = idx >> 5;
      int d0 = dg*4;
      f32x4 v = *(const f32x4*)&qkv[(tok0 + key0 + key)*QKV_N + 2048 + h*64 + d0];
      #pragma unroll
      for (int m=0;m<4;m++){
        _Float16 hh = (_Float16)v[m];
        Vhi[(d0+m)*32 + key] = hh;
        Vlo[(d0+m)*32 + key] = (_Float16)(v[m]-(float)hh);
      }
    }
    __syncthreads();
    // S = Q K^T (3-product split)
    f32x4 sacc[2][2] = {};
    #pragma unroll
    for (int p=0;p<2;p++){
      h16x8 qh[2], ql[2], kh[2], kl[2];
      #pragma unroll
      for (int i=0;i<2;i++){
        qh[i] = *(const h16x8*)&Qhi[(p*128 + wvx*32 + i*16 + lrow)*32 + quad*8];
        ql[i] = *(const h16x8*)&Qlo[(p*128 + wvx*32 + i*16 + lrow)*32 + quad*8];
      }
      #pragma unroll
      for (int j=0;j<2;j++){
        kh[j] = *(const h16x8*)&Khi[(p*32 + j*16 + lrow)*32 + quad*8];
        kl[j] = *(const h16x8*)&Klo[(p*32 + j*16 + lrow)*32 + quad*8];
      }
      #pragma unroll
      for (int i=0;i<2;i++)
        #pragma unroll
        for (int j=0;j<2;j++){
          sacc[i][j] = mfma16(qh[i], kh[j], sacc[i][j]);
          sacc[i][j] = mfma16(qh[i], kl[j], sacc[i][j]);
          sacc[i][j] = mfma16(ql[i], kh[j], sacc[i][j]);
        }
    }
    // online softmax per row
    #pragma unroll
    for (int i=0;i<2;i++){
      #pragma unroll
      for (int r=0;r<4;r++){
        int qrow = q0 + wvx*32 + i*16 + quad*4 + r;
        #pragma unroll
        for (int j=0;j<2;j++){
          float s = sacc[i][j][r] * 0.125f;
          if (useMask) s += ldin(mask, (size_t)qrow*S_LEN + key0 + j*16 + lrow, is32);
          sacc[i][j][r] = s;
        }
        float mx = fmaxf(sacc[i][0][r], sacc[i][1][r]);
        #pragma unroll
        for (int mm=1; mm<=8; mm<<=1) mx = fmaxf(mx, __shfl_xor(mx, mm, 64));
        float mnew = fmaxf(mrun[i][r], mx);
        float alpha = __expf(mrun[i][r] - mnew);
        float ps = 0.f;
        #pragma unroll
        for (int j=0;j<2;j++){
          float p = __expf(sacc[i][j][r] - mnew);
          sacc[i][j][r] = p;
          ps += p;
        }
        #pragma unroll
        for (int mm=1; mm<=8; mm<<=1) ps += __shfl_xor(ps, mm, 64);
        lrun[i][r] = lrun[i][r]*alpha + ps;
        mrun[i][r] = mnew;
        #pragma unroll
        for (int j=0;j<4;j++) oacc[i][j][r] *= alpha;
        int prow = wvx*32 + i*16 + quad*4 + r;
        #pragma unroll
        for (int j=0;j<2;j++){
          int key = j*16 + lrow;
          float pv = sacc[i][j][r];
          _Float16 ph = (_Float16)pv;
          Phi[prow*32 + key] = ph;
          Plo[prow*32 + key] = (_Float16)(pv - (float)ph);
        }
      }
    }
    __syncthreads();   // make Phi/Plo writes visible before fragment reads
    // O += P V (3-product split)
    {
      h16x8 pf[2], pl[2], vh[4], vl[4];
      #pragma unroll
      for (int i=0;i<2;i++){
        pf[i] = *(const h16x8*)&Phi[(wvx*32 + i*16 + lrow)*32 + quad*8];
        pl[i] = *(const h16x8*)&Plo[(wvx*32 + i*16 + lrow)*32 + quad*8];
      }
      #pragma unroll
      for (int j=0;j<4;j++){
        vh[j] = *(const h16x8*)&Vhi[(j*16 + lrow)*32 + quad*8];
        vl[j] = *(const h16x8*)&Vlo[(j*16 + lrow)*32 + quad*8];
      }
      #pragma unroll
      for (int i=0;i<2;i++)
        #pragma unroll
        for (int j=0;j<4;j++){
          oacc[i][j] = mfma16(pf[i], vh[j], oacc[i][j]);
          oacc[i][j] = mfma16(pf[i], vl[j], oacc[i][j]);
          oacc[i][j] = mfma16(pl[i], vh[j], oacc[i][j]);
        }
    }
  }
  #pragma unroll
  for (int i=0;i<2;i++)
    #pragma unroll
    for (int j=0;j<4;j++)
      #pragma unroll
      for (int r=0;r<4;r++){
        int row = q0 + wvx*32 + i*16 + quad*4 + r;
        int col = h*64 + j*16 + lrow;
        aout[(tok0 + row)*H_DIM + col] = oacc[i][j][r] / lrun[i][r];
      }
}

// ---------------- RMSNorm #2 + router (fp32 logits, top-2) ----------------
__global__ __launch_bounds__(256) void k_rms2_router(const float* __restrict__ x1, const void* __restrict__ w,
    const void* __restrict__ rw, _Float16* __restrict__ h2,
    int* __restrict__ tok_e, float* __restrict__ tok_w, int* __restrict__ counts,
    const int* __restrict__ df){
  const int is32 = *df;
  int t = blockIdx.x, tid = threadIdx.x;
  f32x4 v = *(const f32x4*)&x1[(size_t)t*H_DIM + tid*4];
  float ss = v[0]*v[0]+v[1]*v[1]+v[2]*v[2]+v[3]*v[3];
  #pragma unroll
  for (int off=32; off>0; off>>=1) ss += __shfl_down(ss, off, 64);
  __shared__ float red[4];
  __shared__ float lgs[32];
  if ((tid&63)==0) red[tid>>6] = ss;
  __syncthreads();
  float rstd = rsqrt_acc((red[0]+red[1]+red[2]+red[3])*(1.0f/H_DIM) + 1e-6f);
  float hv[4];
  h16x4 hst;
  #pragma unroll
  for (int m=0;m<4;m++){ hv[m] = v[m]*rstd*ldin(w, tid*4+m, is32); hst[m] = (_Float16)hv[m]; }
  *(h16x4*)&h2[(size_t)t*H_DIM + tid*4] = hst;
  float part[8] = {0,0,0,0,0,0,0,0};
  #pragma unroll
  for (int m=0;m<4;m++){
    size_t c = (size_t)(tid*4 + m)*8;
    #pragma unroll
    for (int e=0;e<8;e++) part[e] += hv[m]*ldin(rw, c+e, is32);
  }
  #pragma unroll
  for (int e=0;e<8;e++){
    #pragma unroll
    for (int off=32; off>0; off>>=1) part[e] += __shfl_down(part[e], off, 64);
  }
  if ((tid&63)==0){
    #pragma unroll
    for (int e=0;e<8;e++) lgs[(tid>>6)*8 + e] = part[e];
  }
  __syncthreads();
  if (tid==0){
    float lg[8];
    #pragma unroll
    for (int e=0;e<8;e++) lg[e] = lgs[e] + lgs[8+e] + lgs[16+e] + lgs[24+e];
    int e0 = 0;
    #pragma unroll
    for (int e=1;e<8;e++) if (lg[e] > lg[e0]) e0 = e;
    int e1 = (e0==0) ? 1 : 0;
    #pragma unroll
    for (int e=0;e<8;e++) if (e != e0 && lg[e] > lg[e1]) e1 = e;
    float d = expf(lg[e1] - lg[e0]);
    float w0 = 1.0f/(1.0f + d);
    float w1 = d * w0;
    tok_e[t*2] = e0; tok_e[t*2+1] = e1;
    tok_w[t*2] = w0; tok_w[t*2+1] = w1;
    atomicAdd(&counts[e0], 1);
    atomicAdd(&counts[e1], 1);
  }
}

// ---------------- expert offsets (padded prefix) ----------------
__global__ void k_offsets(const int* __restrict__ counts, int* __restrict__ offs, int* __restrict__ fillpos){
  if (threadIdx.x == 0 && blockIdx.x == 0){
    int o = 0;
    for (int e=0;e<8;e++){
      offs[e] = o; fillpos[e] = o;
      o += (counts[e] + 127) & ~127;
    }
    offs[8] = o;
  }
}

// ---------------- fill compact token lists ----------------
__global__ __launch_bounds__(256) void k_fill(const int* __restrict__ tok_e, const float* __restrict__ tok_w,
    int* __restrict__ fillpos, int* __restrict__ list_ts, float* __restrict__ list_w){
  int t = blockIdx.x*256 + threadIdx.x;
  if (t >= T_TOK) return;
  #pragma unroll
  for (int s=0;s<2;s++){
    int e = tok_e[t*2+s];
    int p = atomicAdd(&fillpos[e], 1);
    list_ts[p] = t*2 + s;
    list_w[p] = tok_w[t*2+s];
  }
}

// ---------------- gathered gate+up GEMM fused with SiLU; B native [K][N] ----------
// B tile in LDS: stride 40, octet-XOR swizzle -> staging writes 4-way max
__global__ __launch_bounds__(256) void k_gemm_gu(const _Float16* __restrict__ h2, const void* __restrict__ guw,
    _Float16* __restrict__ act, const int* __restrict__ list_ts,
    const int* __restrict__ counts, const int* __restrict__ offs, const int* __restrict__ df){
  const int is32 = *df;
  int m0 = blockIdx.y<<7;
  if (m0 >= offs[8]) return;
  int e = 0;
  while (m0 >= offs[e+1]) e++;
  int base = offs[e], cnt = counts[e];
  if (m0 >= base + cnt) return;
  __shared__ __align__(16) _Float16 As[128*32], Bg[64*40], Bu[64*40];
  __shared__ int rowtok[128];
  int tid = threadIdx.x;
  if (tid < 128){
    int mc = min(m0 + tid, base + cnt - 1);
    rowtok[tid] = list_ts[mc] >> 1;
  }
  __syncthreads();
  int lane = tid&63, wvx = tid>>6, wr = wvx>>1, wc = wvx&1, quad = lane>>4, lrow = lane&15;
  int n0 = blockIdx.x<<6;
  size_t ebase = (size_t)e*H_DIM*4096;
  f32x4 ag[4][2] = {}, au[4][2] = {};
  for (int k0=0; k0<1024; k0+=32){
    #pragma unroll
    for (int it=0; it<2; it++){
      int ch = it*256 + tid;
      int r = ch>>2, c = ch&3;
      *(i32x4*)&As[ch*8] = *(const i32x4*)&h2[(size_t)rowtok[r]*H_DIM + k0 + c*8];
    }
    // B staging: k = tid>>3 (0..31), g = tid&7; coalesced 16B loads; swizzled store
    {
      int k = tid>>3, g = tid&7;
      size_t rowb = ebase + (size_t)(k0+k)*4096;
      int ks = kslot_sw(k, g);
      _Float16 tg[8], tu[8];
      if (is32){
        const float* gf = (const float*)guw;
        f32x4 a0 = *(const f32x4*)&gf[rowb + n0 + g*8];
        f32x4 a1 = *(const f32x4*)&gf[rowb + n0 + g*8 + 4];
        f32x4 b0 = *(const f32x4*)&gf[rowb + 2048 + n0 + g*8];
        f32x4 b1 = *(const f32x4*)&gf[rowb + 2048 + n0 + g*8 + 4];
        #pragma unroll
        for (int i=0;i<4;i++){ tg[i]=(_Float16)a0[i]; tg[4+i]=(_Float16)a1[i];
                               tu[i]=(_Float16)b0[i]; tu[4+i]=(_Float16)b1[i]; }
      } else {
        const u16* gb = (const u16*)guw;
        u16x4 a0 = *(const u16x4*)&gb[rowb + n0 + g*8];
        u16x4 a1 = *(const u16x4*)&gb[rowb + n0 + g*8 + 4];
        u16x4 b0 = *(const u16x4*)&gb[rowb + 2048 + n0 + g*8];
        u16x4 b1 = *(const u16x4*)&gb[rowb + 2048 + n0 + g*8 + 4];
        #pragma unroll
        for (int i=0;i<4;i++){ tg[i]=(_Float16)bf2f(a0[i]); tg[4+i]=(_Float16)bf2f(a1[i]);
                               tu[i]=(_Float16)bf2f(b0[i]); tu[4+i]=(_Float16)bf2f(b1[i]); }
      }
      #pragma unroll
      for (int i=0;i<8;i++){
        int n = g*8 + i;
        Bg[n*40 + ks] = tg[i];
        Bu[n*40 + ks] = tu[i];
      }
    }
    __syncthreads();
    h16x8 a[4], bg[2], bu[2];
    #pragma unroll
    for (int i=0;i<4;i++) a[i] = *(const h16x8*)&As[(wr*64 + i*16 + lrow)*32 + quad*8];
    #pragma unroll
    for (int j=0;j<2;j++){
      int n = wc*32 + j*16 + lrow;
      int oct = (quad ^ ((n>>3)&3))*8;
      bg[j] = *(const h16x8*)&Bg[n*40 + oct];
      bu[j] = *(const h16x8*)&Bu[n*40 + oct];
    }
    #pragma unroll
    for (int i=0;i<4;i++)
      #pragma unroll
      for (int j=0;j<2;j++){
        ag[i][j] = mfma16(a[i], bg[j], ag[i][j]);
        au[i][j] = mfma16(a[i], bu[j], au[i][j]);
      }
    __syncthreads();
  }
  #pragma unroll
  for (int i=0;i<4;i++)
    #pragma unroll
    for (int j=0;j<2;j++)
      #pragma unroll
      for (int r=0;r<4;r++){
        int row = m0 + wr*64 + i*16 + quad*4 + r;
        int col = n0 + wc*32 + j*16 + lrow;
        float g = ag[i][j][r], u = au[i][j][r];
        float sv = g / (1.0f + __expf(-g));
        act[(size_t)row*INTER_DIM + col] = (_Float16)(sv * u);
      }
}

// ---------------- down GEMM (B native [K][N], swizzled tiles), scatter ----------
__global__ __launch_bounds__(256) void k_gemm_down(const _Float16* __restrict__ act, const void* __restrict__ dw,
    _Float16* __restrict__ slotbuf, const int* __restrict__ list_ts, const float* __restrict__ list_w,
    const int* __restrict__ counts, const int* __restrict__ offs, const int* __restrict__ df){
  const int is32 = *df;
  int m0 = blockIdx.y<<7;
  if (m0 >= offs[8]) return;
  int e = 0;
  while (m0 >= offs[e+1]) e++;
  int base = offs[e], cnt = counts[e];
  if (m0 >= base + cnt) return;
  __shared__ __align__(16) _Float16 As[128*32], Bs[128*40];
  int tid = threadIdx.x, lane = tid&63, wvx = tid>>6;
  int wr = wvx>>1, wc = wvx&1, quad = lane>>4, lrow = lane&15;
  int n0 = blockIdx.x<<7;
  size_t ebase = (size_t)e*INTER_DIM*H_DIM;
  f32x4 acc[4][4] = {};
  for (int k0=0; k0<2048; k0+=32){
    #pragma unroll
    for (int it=0; it<2; it++){
      int ch = it*256 + tid;
      int r = ch>>2, c = ch&3;
      *(i32x4*)&As[ch*8] = *(const i32x4*)&act[(size_t)(m0+r)*INTER_DIM + k0 + c*8];
    }
    // B staging: 2 passes over n (64 each); k = tid>>3, g = tid&7; swizzled store
    {
      int k = tid>>3, g = tid&7;
      size_t rowb = ebase + (size_t)(k0+k)*H_DIM;
      int ks = kslot_sw(k, g);
      #pragma unroll
      for (int p=0;p<2;p++){
        _Float16 tb[8];
        if (is32){
          const float* bf = (const float*)dw;
          f32x4 a0 = *(const f32x4*)&bf[rowb + n0 + p*64 + g*8];
          f32x4 a1 = *(const f32x4*)&bf[rowb + n0 + p*64 + g*8 + 4];
          #pragma unroll
          for (int i=0;i<4;i++){ tb[i]=(_Float16)a0[i]; tb[4+i]=(_Float16)a1[i]; }
        } else {
          const u16* bb = (const u16*)dw;
          u16x4 a0 = *(const u16x4*)&bb[rowb + n0 + p*64 + g*8];
          u16x4 a1 = *(const u16x4*)&bb[rowb + n0 + p*64 + g*8 + 4];
          #pragma unroll
          for (int i=0;i<4;i++){ tb[i]=(_Float16)bf2f(a0[i]); tb[4+i]=(_Float16)bf2f(a1[i]); }
        }
        #pragma unroll
        for (int i=0;i<8;i++){
          int n = p*64 + g*8 + i;
          Bs[n*40 + ks] = tb[i];
        }
      }
    }
    __syncthreads();
    h16x8 a[4], b[4];
    #pragma unroll
    for (int i=0;i<4;i++) a[i] = *(const h16x8*)&As[(wr*64 + i*16 + lrow)*32 + quad*8];
    #pragma unroll
    for (int j=0;j<4;j++){
      int n = wc*64 + j*16 + lrow;
      b[j] = *(const h16x8*)&Bs[n*40 + ((quad ^ ((n>>3)&3))*8)];
    }
    #pragma unroll
    for (int i=0;i<4;i++)
      #pragma unroll
      for (int j=0;j<4;j++)
        acc[i][j] = mfma16(a[i], b[j], acc[i][j]);
    __syncthreads();
  }
  #pragma unroll
  for (int i=0;i<4;i++)
    #pragma unroll
    for (int r=0;r<4;r++){
      int m = m0 + wr*64 + i*16 + quad*4 + r;
      if (m < base + cnt){
        int ts = list_ts[m];
        float wgt = list_w[m];
        #pragma unroll
        for (int j=0;j<4;j++){
          int col = n0 + wc*64 + j*16 + lrow;
          slotbuf[(size_t)ts*H_DIM + col] = (_Float16)(wgt * acc[i][j][r]);
        }
      }
    }
}

// ---------------- final residual add -> dual-dtype out ----------------
__global__ __launch_bounds__(256) void k_final(const float* __restrict__ x1, const _Float16* __restrict__ slot,
                                               void* __restrict__ outv, const int* __restrict__ df){
  const int is32 = *df;
  int i4 = (blockIdx.x*256 + threadIdx.x)*4;
  int t = i4 >> 10, c = i4 & 1023;
  f32x4 a = *(const f32x4*)&x1[i4];
  h16x4 s0 = *(const h16x4*)&slot[(size_t)(t*2)*H_DIM + c];
  h16x4 s1 = *(const h16x4*)&slot[(size_t)(t*2+1)*H_DIM + c];
  if (is32){
    f32x4 o;
    #pragma unroll
    for (int m=0;m<4;m++) o[m] = a[m] + (float)s0[m] + (float)s1[m];
    *(f32x4*)&((float*)outv)[i4] = o;
  } else {
    u16x4 o;
    #pragma unroll
    for (int m=0;m<4;m++) o[m] = f2bf(a[m] + (float)s0[m] + (float)s1[m]);
    *(u16x4*)&((u16*)outv)[i4] = o;
  }
}

extern "C" void kernel_launch(void* const* d_in, const int* in_sizes, int n_in,
                              void* d_out, int out_size, void* d_ws, size_t ws_size,
                              hipStream_t stream){
  (void)in_sizes; (void)n_in; (void)out_size; (void)ws_size;
  const void* x    = d_in[0];
  const void* mask = d_in[1];
  const void* ln1  = d_in[2];
  const void* ln2  = d_in[3];
  const void* qkvw = d_in[4];
  const void* ow   = d_in[5];
  const void* rw   = d_in[6];
  const void* guw  = d_in[7];
  const void* dww  = d_in[8];

  char* ws = (char*)d_ws;
  size_t off = 0;
  auto alloc = [&](size_t b)->void*{ void* p = ws + off; off = (off + b + 255) & ~(size_t)255; return p; };
  int* meta            = (int*)alloc(32*sizeof(int));
  _Float16* qkv_wt     = (_Float16*)alloc((size_t)3072*1024*2);
  _Float16* o_wt       = (_Float16*)alloc((size_t)1024*1024*2);
  float* hbuf          = (float*)alloc((size_t)4096*1024*4);    // h, then attn-out
  float* qkvbuf        = (float*)alloc((size_t)4096*3072*4);    // qkv fp32; later h2+act
  float* x1            = (float*)alloc((size_t)4096*1024*4);
  _Float16* slotbuf    = (_Float16*)alloc((size_t)4096*2*1024*2);
  int* list_ts         = (int*)alloc(MAXROWS*4);
  float* list_w        = (float*)alloc(MAXROWS*4);
  int* tok_e           = (int*)alloc((size_t)4096*2*4);
  float* tok_w         = (float*)alloc((size_t)4096*2*4);
  // total ~105 MB

  int* counts = meta;
  int* offs   = meta + 8;
  int* fillpos= meta + 17;
  int* flag   = meta + 25;
  int* dflag  = meta + 26;
  _Float16* h2  = (_Float16*)qkvbuf;                                // 8 MB
  _Float16* act = (_Float16*)((char*)qkvbuf + (size_t)4096*1024*2); // 37.75 MB, fits in qkvbuf

  hipMemsetAsync(meta, 0, 32*sizeof(int), stream);
  k_detect<<<dim3(1), dim3(64), 0, stream>>>((const uint32_t*)x, dflag);
  k_transpose_cast<<<dim3(3072/32, 1024/32, 1), 256, 0, stream>>>(qkvw, qkv_wt, 1024, 3072, dflag);
  k_transpose_cast<<<dim3(1024/32, 1024/32, 1), 256, 0, stream>>>(ow, o_wt, 1024, 1024, dflag);
  k_maskchk<<<dim3(1024), 256, 0, stream>>>(mask, flag, dflag);
  k_rms1<<<dim3(4096), 256, 0, stream>>>(x, ln1, hbuf, dflag);
  k_gemm_splitA<0><<<dim3(24, 32), 256, 0, stream>>>(hbuf, qkv_wt, qkvbuf, nullptr, 3072, 1024, dflag);
  k_attn<<<dim3(8, 64), 256, 0, stream>>>(qkvbuf, mask, flag, hbuf, dflag);
  k_gemm_splitA<1><<<dim3(8, 32), 256, 0, stream>>>(hbuf, o_wt, x1, x, 1024, 1024, dflag);
  k_rms2_router<<<dim3(4096), 256, 0, stream>>>(x1, ln2, rw, h2, tok_e, tok_w, counts, dflag);
  k_offsets<<<dim3(1), dim3(64), 0, stream>>>(counts, offs, fillpos);
  k_fill<<<dim3(16), 256, 0, stream>>>(tok_e, tok_w, fillpos, list_ts, list_w);
  k_gemm_gu<<<dim3(32, 72), 256, 0, stream>>>(h2, guw, act, list_ts, counts, offs, dflag);
  k_gemm_down<<<dim3(8, 72), 256, 0, stream>>>(act, dww, slotbuf, list_ts, list_w, counts, offs, dflag);
  k_final<<<dim3(4096), 256, 0, stream>>>(x1, slotbuf, d_out, dflag);
}

// Round 4
// 921.980 us; speedup vs baseline: 1.1981x; 1.0473x over previous
//
#include <hip/hip_runtime.h>
#include <cstdint>
#include <cmath>

// Problem constants (B=4, S=1024)
#define T_TOK 4096
#define H_DIM 1024
#define QKV_N 3072
#define S_LEN 1024
#define INTER_DIM 2048
#define MAXROWS 9216   // 2*T + 8*127 padding, rounded

typedef unsigned short u16;
using f32x4 = __attribute__((ext_vector_type(4))) float;
using h16x8 = __attribute__((ext_vector_type(8))) _Float16;
using h16x4 = __attribute__((ext_vector_type(4))) _Float16;
using i32x4 = __attribute__((ext_vector_type(4))) int;
using u16x4 = __attribute__((ext_vector_type(4))) u16;
using u16x8 = __attribute__((ext_vector_type(8))) u16;

__device__ __forceinline__ float bf2f(u16 u){ return __uint_as_float(((uint32_t)u)<<16); }
__device__ __forceinline__ u16 f2bf(float f){
  uint32_t x = __float_as_uint(f);
  uint32_t r = x + 0x7FFFu + ((x>>16)&1u);
  return (u16)(r>>16);
}
__device__ __forceinline__ f32x4 mfma16(h16x8 a, h16x8 b, f32x4 c){
  return __builtin_amdgcn_mfma_f32_16x16x32_f16(a,b,c,0,0,0);
}
__device__ __forceinline__ float rsqrt_acc(float v){
  float r = rsqrtf(v);
  r = r*(1.5f - 0.5f*v*r*r);
  r = r*(1.5f - 0.5f*v*r*r);
  return r;
}
// dual-dtype scalar input read
__device__ __forceinline__ float ldin(const void* p, size_t i, int is32){
  return is32 ? ((const float*)p)[i] : bf2f(((const u16*)p)[i]);
}
// swizzled k-slot for stride-40 B tiles (legacy path)
__device__ __forceinline__ int kslot_sw(int k, int noct){
  return (k&7) | (((k>>3) ^ (noct&3))<<3);
}
// async global->LDS, 16B per lane; lds base must be wave-uniform, lanes land at base+lane*16
__device__ __forceinline__ void gll16(const void* g, void* l){
  __builtin_amdgcn_global_load_lds(
      (const __attribute__((address_space(1))) void*)g,
      (__attribute__((address_space(3))) void*)l, 16, 0, 0);
}

// ---------------- dtype detection: fp32 exponent fields of N(0,1) data ----------------
__global__ void k_detect(const uint32_t* __restrict__ x, int* __restrict__ dflag){
  uint32_t u = x[threadIdx.x];
  int e = (u>>23)&0xFF;
  int ok = (e>=103 && e<=150);            // |f| in [2^-24, 2^23]
  unsigned long long m = __ballot(ok);
  if (threadIdx.x==0) *dflag = (__popcll(m) >= 48) ? 1 : 0;
}

// ---------------- vectorized transpose + cast to f16: src [R][C] -> dst [C][R] ------
// 64x64 tiles; conflict-free LDS (stride 65); 16B global loads/stores
__global__ __launch_bounds__(256) void k_trans2(const void* __restrict__ src,
    _Float16* __restrict__ dst, int R, int C, const int* __restrict__ df){
  const int is32 = *df;
  __shared__ _Float16 t[64][65];
  size_t bo = (size_t)blockIdx.z * R * C;
  int c0 = blockIdx.x<<6, r0 = blockIdx.y<<6;
  int ty = threadIdx.x>>3, tx = threadIdx.x&7;   // ty 0..31, tx 0..7
  #pragma unroll
  for (int rr=0; rr<2; rr++){
    int r = rr*32 + ty;
    size_t gi = bo + (size_t)(r0+r)*C + c0 + tx*8;
    _Float16 v[8];
    if (is32){
      f32x4 a0 = *(const f32x4*)&((const float*)src)[gi];
      f32x4 a1 = *(const f32x4*)&((const float*)src)[gi+4];
      #pragma unroll
      for (int i=0;i<4;i++){ v[i]=(_Float16)a0[i]; v[4+i]=(_Float16)a1[i]; }
    } else {
      u16x8 a = *(const u16x8*)&((const u16*)src)[gi];
      #pragma unroll
      for (int i=0;i<8;i++) v[i]=(_Float16)bf2f(a[i]);
    }
    #pragma unroll
    for (int i=0;i<8;i++) t[r][tx*8+i] = v[i];
  }
  __syncthreads();
  #pragma unroll
  for (int rr=0; rr<2; rr++){
    int n = rr*32 + ty;
    h16x8 v;
    #pragma unroll
    for (int i=0;i<8;i++) v[i] = t[tx*8+i][n];
    *(h16x8*)&dst[bo + (size_t)(c0+n)*R + r0 + tx*8] = v;
  }
}

// ---------------- mask all-zero check ----------------
__global__ __launch_bounds__(256) void k_maskchk(const void* __restrict__ m, int* __restrict__ flag,
                                                 const int* __restrict__ df){
  const int is32 = *df;
  int i = (blockIdx.x*256 + threadIdx.x)*4;
  int nz = 0;
  if (is32){
    f32x4 v = *(const f32x4*)&((const float*)m)[i];
    nz = (v[0]!=0.f)||(v[1]!=0.f)||(v[2]!=0.f)||(v[3]!=0.f);
  } else {
    u16x4 v = *(const u16x4*)&((const u16*)m)[i];
    nz = ((v[0]|v[1]|v[2]|v[3]) & 0x7FFF) != 0;
  }
  if (nz) atomicOr(flag, 1);
}

// ---------------- RMSNorm #1: x -> fp32 h ----------------
__global__ __launch_bounds__(256) void k_rms1(const void* __restrict__ x, const void* __restrict__ w,
                                              float* __restrict__ h, const int* __restrict__ df){
  const int is32 = *df;
  int t = blockIdx.x, tid = threadIdx.x;
  size_t base = (size_t)t*H_DIM + tid*4;
  float f[4];
  #pragma unroll
  for (int m=0;m<4;m++) f[m] = ldin(x, base+m, is32);
  float ss = f[0]*f[0] + f[1]*f[1] + f[2]*f[2] + f[3]*f[3];
  #pragma unroll
  for (int off=32; off>0; off>>=1) ss += __shfl_down(ss, off, 64);
  __shared__ float red[4];
  if ((tid & 63) == 0) red[tid>>6] = ss;
  __syncthreads();
  float rstd = rsqrt_acc((red[0]+red[1]+red[2]+red[3]) * (1.0f/H_DIM) + 1e-6f);
  f32x4 o;
  #pragma unroll
  for (int m=0;m<4;m++) o[m] = f[m]*rstd*ldin(w, tid*4+m, is32);
  *(f32x4*)&h[base] = o;
}

// ---------------- high-precision GEMM: fp32 A split to f16 hi/lo, f16 B (exact) ----
template<int EPI>
__global__ __launch_bounds__(256) void k_gemm_splitA(const float* __restrict__ A,
    const _Float16* __restrict__ Bt, float* __restrict__ C, const void* __restrict__ res,
    int N, int K, const int* __restrict__ df){
  const int is32 = *df;
  __shared__ __align__(16) _Float16 Ahi[128*32];
  __shared__ __align__(16) _Float16 Alo[128*32];
  __shared__ __align__(16) _Float16 Bs[128*32];
  int tid = threadIdx.x, lane = tid&63, wvx = tid>>6;
  int wr = wvx>>1, wc = wvx&1, quad = lane>>4, lrow = lane&15;
  int m0 = blockIdx.y<<7, n0 = blockIdx.x<<7;
  f32x4 acc[4][4] = {};
  for (int k0=0; k0<K; k0+=32){
    #pragma unroll
    for (int it=0; it<4; it++){
      int ch = it*256 + tid;
      int r = ch>>3, g = ch&7;
      f32x4 v = *(const f32x4*)&A[(size_t)(m0+r)*K + k0 + g*4];
      h16x4 hi, lo;
      #pragma unroll
      for (int q2=0;q2<4;q2++){
        _Float16 hh = (_Float16)v[q2];
        hi[q2] = hh;
        lo[q2] = (_Float16)(v[q2] - (float)hh);
      }
      *(h16x4*)&Ahi[r*32 + g*4] = hi;
      *(h16x4*)&Alo[r*32 + g*4] = lo;
    }
    #pragma unroll
    for (int it=0; it<2; it++){
      int ch = it*256 + tid;
      gll16(&Bt[(size_t)(n0 + (ch>>2))*K + k0 + (ch&3)*8], &Bs[(size_t)(it*256 + wvx*64)*8]);
    }
    __syncthreads();
    h16x8 ah[4], al[4], bb[4];
    #pragma unroll
    for (int i=0;i<4;i++){
      ah[i] = *(const h16x8*)&Ahi[(wr*64 + i*16 + lrow)*32 + quad*8];
      al[i] = *(const h16x8*)&Alo[(wr*64 + i*16 + lrow)*32 + quad*8];
    }
    #pragma unroll
    for (int j=0;j<4;j++) bb[j] = *(const h16x8*)&Bs[(wc*64 + j*16 + lrow)*32 + quad*8];
    #pragma unroll
    for (int i=0;i<4;i++)
      #pragma unroll
      for (int j=0;j<4;j++){
        acc[i][j] = mfma16(ah[i], bb[j], acc[i][j]);
        acc[i][j] = mfma16(al[i], bb[j], acc[i][j]);
      }
    __syncthreads();
  }
  #pragma unroll
  for (int i=0;i<4;i++)
    #pragma unroll
    for (int j=0;j<4;j++){
      int col = n0 + wc*64 + j*16 + lrow;
      #pragma unroll
      for (int r=0;r<4;r++){
        int row = m0 + wr*64 + i*16 + quad*4 + r;
        size_t idx = (size_t)row*N + col;
        float v = acc[i][j][r];
        if (EPI==1) v += ldin(res, idx, is32);
        C[idx] = v;
      }
    }
}

// ---------------- flash attention, fp32 qkv in, split-f16 MFMA, fp32 out ----------
__global__ __launch_bounds__(256) void k_attn(const float* __restrict__ qkv, const void* __restrict__ mask,
                                              const int* __restrict__ mflag, float* __restrict__ aout,
                                              const int* __restrict__ df){
  const int is32 = *df;
  __shared__ __align__(16) _Float16 Qhi[2*128*32], Qlo[2*128*32];
  __shared__ __align__(16) _Float16 Khi[2*32*32],  Klo[2*32*32];
  __shared__ __align__(16) _Float16 Vhi[64*32],    Vlo[64*32];
  __shared__ __align__(16) _Float16 Phi[128*32],   Plo[128*32];
  int qt = blockIdx.x, bh = blockIdx.y;
  int b = bh>>4, h = bh&15;
  int tid = threadIdx.x, lane = tid&63, wvx = tid>>6, quad = lane>>4, lrow = lane&15;
  size_t tok0 = (size_t)b*S_LEN;
  int q0 = qt<<7;
  #pragma unroll
  for (int it=0; it<8; it++){
    int idx = it*256 + tid;
    int r = idx>>4, g = idx&15;
    int d0 = g*4, p = g>>3;
    f32x4 v = *(const f32x4*)&qkv[(tok0 + q0 + r)*QKV_N + h*64 + d0];
    h16x4 hi, lo;
    #pragma unroll
    for (int m=0;m<4;m++){ _Float16 hh=(_Float16)v[m]; hi[m]=hh; lo[m]=(_Float16)(v[m]-(float)hh); }
    *(h16x4*)&Qhi[(p*128 + r)*32 + (d0&31)] = hi;
    *(h16x4*)&Qlo[(p*128 + r)*32 + (d0&31)] = lo;
  }
  int useMask = *mflag;
  float mrun[2][4], lrun[2][4];
  f32x4 oacc[2][4] = {};
  #pragma unroll
  for (int i=0;i<2;i++)
    #pragma unroll
    for (int r=0;r<4;r++){ mrun[i][r] = -INFINITY; lrun[i][r] = 0.f; }

  for (int kt=0; kt<32; kt++){
    int key0 = kt*32;
    __syncthreads();
    #pragma unroll
    for (int it=0; it<2; it++){
      int idx = it*256 + tid;
      int key = idx>>4, g = idx&15;
      int d0 = g*4, p = g>>3;
      f32x4 v = *(const f32x4*)&qkv[(tok0 + key0 + key)*QKV_N + 1024 + h*64 + d0];
      h16x4 hi, lo;
      #pragma unroll
      for (int m=0;m<4;m++){ _Float16 hh=(_Float16)v[m]; hi[m]=hh; lo[m]=(_Float16)(v[m]-(float)hh); }
      *(h16x4*)&Khi[(p*32 + key)*32 + (d0&31)] = hi;
      *(h16x4*)&Klo[(p*32 + key)*32 + (d0&31)] = lo;
    }
    #pragma unroll
    for (int it=0; it<2; it++){
      int idx = it*256 + tid;
      int key = idx & 31, dg = idx >> 5;
      int d0 = dg*4;
      f32x4 v = *(const f32x4*)&qkv[(tok0 + key0 + key)*QKV_N + 2048 + h*64 + d0];
      #pragma unroll
      for (int m=0;m<4;m++){
        _Float16 hh = (_Float16)v[m];
        Vhi[(d0+m)*32 + key] = hh;
        Vlo[(d0+m)*32 + key] = (_Float16)(v[m]-(float)hh);
      }
    }
    __syncthreads();
    f32x4 sacc[2][2] = {};
    #pragma unroll
    for (int p=0;p<2;p++){
      h16x8 qh[2], ql[2], kh[2], kl[2];
      #pragma unroll
      for (int i=0;i<2;i++){
        qh[i] = *(const h16x8*)&Qhi[(p*128 + wvx*32 + i*16 + lrow)*32 + quad*8];
        ql[i] = *(const h16x8*)&Qlo[(p*128 + wvx*32 + i*16 + lrow)*32 + quad*8];
      }
      #pragma unroll
      for (int j=0;j<2;j++){
        kh[j] = *(const h16x8*)&Khi[(p*32 + j*16 + lrow)*32 + quad*8];
        kl[j] = *(const h16x8*)&Klo[(p*32 + j*16 + lrow)*32 + quad*8];
      }
      #pragma unroll
      for (int i=0;i<2;i++)
        #pragma unroll
        for (int j=0;j<2;j++){
          sacc[i][j] = mfma16(qh[i], kh[j], sacc[i][j]);
          sacc[i][j] = mfma16(qh[i], kl[j], sacc[i][j]);
          sacc[i][j] = mfma16(ql[i], kh[j], sacc[i][j]);
        }
    }
    #pragma unroll
    for (int i=0;i<2;i++){
      #pragma unroll
      for (int r=0;r<4;r++){
        int qrow = q0 + wvx*32 + i*16 + quad*4 + r;
        #pragma unroll
        for (int j=0;j<2;j++){
          float s = sacc[i][j][r] * 0.125f;
          if (useMask) s += ldin(mask, (size_t)qrow*S_LEN + key0 + j*16 + lrow, is32);
          sacc[i][j][r] = s;
        }
        float mx = fmaxf(sacc[i][0][r], sacc[i][1][r]);
        #pragma unroll
        for (int mm=1; mm<=8; mm<<=1) mx = fmaxf(mx, __shfl_xor(mx, mm, 64));
        float mnew = fmaxf(mrun[i][r], mx);
        float alpha = __expf(mrun[i][r] - mnew);
        float ps = 0.f;
        #pragma unroll
        for (int j=0;j<2;j++){
          float p = __expf(sacc[i][j][r] - mnew);
          sacc[i][j][r] = p;
          ps += p;
        }
        #pragma unroll
        for (int mm=1; mm<=8; mm<<=1) ps += __shfl_xor(ps, mm, 64);
        lrun[i][r] = lrun[i][r]*alpha + ps;
        mrun[i][r] = mnew;
        #pragma unroll
        for (int j=0;j<4;j++) oacc[i][j][r] *= alpha;
        int prow = wvx*32 + i*16 + quad*4 + r;
        #pragma unroll
        for (int j=0;j<2;j++){
          int key = j*16 + lrow;
          float pv = sacc[i][j][r];
          _Float16 ph = (_Float16)pv;
          Phi[prow*32 + key] = ph;
          Plo[prow*32 + key] = (_Float16)(pv - (float)ph);
        }
      }
    }
    __syncthreads();
    {
      h16x8 pf[2], pl[2], vh[4], vl[4];
      #pragma unroll
      for (int i=0;i<2;i++){
        pf[i] = *(const h16x8*)&Phi[(wvx*32 + i*16 + lrow)*32 + quad*8];
        pl[i] = *(const h16x8*)&Plo[(wvx*32 + i*16 + lrow)*32 + quad*8];
      }
      #pragma unroll
      for (int j=0;j<4;j++){
        vh[j] = *(const h16x8*)&Vhi[(j*16 + lrow)*32 + quad*8];
        vl[j] = *(const h16x8*)&Vlo[(j*16 + lrow)*32 + quad*8];
      }
      #pragma unroll
      for (int i=0;i<2;i++)
        #pragma unroll
        for (int j=0;j<4;j++){
          oacc[i][j] = mfma16(pf[i], vh[j], oacc[i][j]);
          oacc[i][j] = mfma16(pf[i], vl[j], oacc[i][j]);
          oacc[i][j] = mfma16(pl[i], vh[j], oacc[i][j]);
        }
    }
  }
  #pragma unroll
  for (int i=0;i<2;i++)
    #pragma unroll
    for (int j=0;j<4;j++)
      #pragma unroll
      for (int r=0;r<4;r++){
        int row = q0 + wvx*32 + i*16 + quad*4 + r;
        int col = h*64 + j*16 + lrow;
        aout[(tok0 + row)*H_DIM + col] = oacc[i][j][r] / lrun[i][r];
      }
}

// ---------------- RMSNorm #2 + router (fp32 logits, top-2) ----------------
__global__ __launch_bounds__(256) void k_rms2_router(const float* __restrict__ x1, const void* __restrict__ w,
    const void* __restrict__ rw, _Float16* __restrict__ h2,
    int* __restrict__ tok_e, float* __restrict__ tok_w, int* __restrict__ counts,
    const int* __restrict__ df){
  const int is32 = *df;
  int t = blockIdx.x, tid = threadIdx.x;
  f32x4 v = *(const f32x4*)&x1[(size_t)t*H_DIM + tid*4];
  float ss = v[0]*v[0]+v[1]*v[1]+v[2]*v[2]+v[3]*v[3];
  #pragma unroll
  for (int off=32; off>0; off>>=1) ss += __shfl_down(ss, off, 64);
  __shared__ float red[4];
  __shared__ float lgs[32];
  if ((tid&63)==0) red[tid>>6] = ss;
  __syncthreads();
  float rstd = rsqrt_acc((red[0]+red[1]+red[2]+red[3])*(1.0f/H_DIM) + 1e-6f);
  float hv[4];
  h16x4 hst;
  #pragma unroll
  for (int m=0;m<4;m++){ hv[m] = v[m]*rstd*ldin(w, tid*4+m, is32); hst[m] = (_Float16)hv[m]; }
  *(h16x4*)&h2[(size_t)t*H_DIM + tid*4] = hst;
  float part[8] = {0,0,0,0,0,0,0,0};
  #pragma unroll
  for (int m=0;m<4;m++){
    size_t c = (size_t)(tid*4 + m)*8;
    #pragma unroll
    for (int e=0;e<8;e++) part[e] += hv[m]*ldin(rw, c+e, is32);
  }
  #pragma unroll
  for (int e=0;e<8;e++){
    #pragma unroll
    for (int off=32; off>0; off>>=1) part[e] += __shfl_down(part[e], off, 64);
  }
  if ((tid&63)==0){
    #pragma unroll
    for (int e=0;e<8;e++) lgs[(tid>>6)*8 + e] = part[e];
  }
  __syncthreads();
  if (tid==0){
    float lg[8];
    #pragma unroll
    for (int e=0;e<8;e++) lg[e] = lgs[e] + lgs[8+e] + lgs[16+e] + lgs[24+e];
    int e0 = 0;
    #pragma unroll
    for (int e=1;e<8;e++) if (lg[e] > lg[e0]) e0 = e;
    int e1 = (e0==0) ? 1 : 0;
    #pragma unroll
    for (int e=0;e<8;e++) if (e != e0 && lg[e] > lg[e1]) e1 = e;
    float d = expf(lg[e1] - lg[e0]);
    float w0 = 1.0f/(1.0f + d);
    float w1 = d * w0;
    tok_e[t*2] = e0; tok_e[t*2+1] = e1;
    tok_w[t*2] = w0; tok_w[t*2+1] = w1;
    atomicAdd(&counts[e0], 1);
    atomicAdd(&counts[e1], 1);
  }
}

// ---------------- expert offsets (padded prefix) ----------------
__global__ void k_offsets(const int* __restrict__ counts, int* __restrict__ offs, int* __restrict__ fillpos){
  if (threadIdx.x == 0 && blockIdx.x == 0){
    int o = 0;
    for (int e=0;e<8;e++){
      offs[e] = o; fillpos[e] = o;
      o += (counts[e] + 127) & ~127;
    }
    offs[8] = o;
  }
}

// ---------------- fill compact token lists ----------------
__global__ __launch_bounds__(256) void k_fill(const int* __restrict__ tok_e, const float* __restrict__ tok_w,
    int* __restrict__ fillpos, int* __restrict__ list_ts, float* __restrict__ list_w){
  int t = blockIdx.x*256 + threadIdx.x;
  if (t >= T_TOK) return;
  #pragma unroll
  for (int s=0;s<2;s++){
    int e = tok_e[t*2+s];
    int p = atomicAdd(&fillpos[e], 1);
    list_ts[p] = t*2 + s;
    list_w[p] = tok_w[t*2+s];
  }
}

// ======== HOT PATH: pre-transposed f16 weights + global_load_lds staging ========

// gate+up GEMM, B^T [e][n=4096][k=1024] f16; tile 128m x (64 gate + 64 up), BK=32
__global__ __launch_bounds__(256) void k_gemm_gu_t(const _Float16* __restrict__ h2,
    const _Float16* __restrict__ gwt, _Float16* __restrict__ act, const int* __restrict__ list_ts,
    const int* __restrict__ counts, const int* __restrict__ offs){
  int m0 = blockIdx.y<<7;
  if (m0 >= offs[8]) return;
  int e = 0;
  while (m0 >= offs[e+1]) e++;
  int base = offs[e], cnt = counts[e];
  if (m0 >= base + cnt) return;
  __shared__ __align__(16) _Float16 As[128*32], Bg[64*32], Bu[64*32];
  __shared__ int rowtok[128];
  int tid = threadIdx.x;
  if (tid < 128) rowtok[tid] = list_ts[min(m0 + tid, base + cnt - 1)] >> 1;
  __syncthreads();
  int lane = tid&63, wvx = tid>>6, wr = wvx>>1, wc = wvx&1, quad = lane>>4, lrow = lane&15;
  int n0 = blockIdx.x<<6;
  const _Float16* Bge = gwt + (size_t)e*4096*1024 + (size_t)n0*1024;
  const _Float16* Bue = gwt + (size_t)e*4096*1024 + (size_t)(2048+n0)*1024;
  // hoist gathered A row bases (k0-independent)
  const _Float16* arow0 = &h2[(size_t)rowtok[tid>>2]*H_DIM + (tid&3)*8];
  const _Float16* arow1 = &h2[(size_t)rowtok[(256+tid)>>2]*H_DIM + (tid&3)*8];
  int bR = tid>>2, bG = tid&3;
  f32x4 ag[4][2] = {}, au[4][2] = {};
  for (int k0=0; k0<1024; k0+=32){
    gll16(arow0 + k0, &As[(size_t)(wvx*64)*8]);
    gll16(arow1 + k0, &As[(size_t)(256 + wvx*64)*8]);
    gll16(&Bge[(size_t)bR*1024 + k0 + bG*8], &Bg[(size_t)(wvx*64)*8]);
    gll16(&Bue[(size_t)bR*1024 + k0 + bG*8], &Bu[(size_t)(wvx*64)*8]);
    __syncthreads();
    h16x8 a[4], bg[2], bu[2];
    #pragma unroll
    for (int i=0;i<4;i++) a[i] = *(const h16x8*)&As[(wr*64 + i*16 + lrow)*32 + quad*8];
    #pragma unroll
    for (int j=0;j<2;j++){
      bg[j] = *(const h16x8*)&Bg[(wc*32 + j*16 + lrow)*32 + quad*8];
      bu[j] = *(const h16x8*)&Bu[(wc*32 + j*16 + lrow)*32 + quad*8];
    }
    #pragma unroll
    for (int i=0;i<4;i++)
      #pragma unroll
      for (int j=0;j<2;j++){
        ag[i][j] = mfma16(a[i], bg[j], ag[i][j]);
        au[i][j] = mfma16(a[i], bu[j], au[i][j]);
      }
    __syncthreads();
  }
  #pragma unroll
  for (int i=0;i<4;i++)
    #pragma unroll
    for (int j=0;j<2;j++)
      #pragma unroll
      for (int r=0;r<4;r++){
        int row = m0 + wr*64 + i*16 + quad*4 + r;
        int col = n0 + wc*32 + j*16 + lrow;
        float g = ag[i][j][r], u = au[i][j][r];
        float sv = g / (1.0f + __expf(-g));
        act[(size_t)row*INTER_DIM + col] = (_Float16)(sv * u);
      }
}

// down GEMM, B^T [e][n=1024][k=2048] f16; tile 128x128, BK=32; scatter epilogue
__global__ __launch_bounds__(256) void k_gemm_down_t(const _Float16* __restrict__ act,
    const _Float16* __restrict__ dwt, _Float16* __restrict__ slotbuf, const int* __restrict__ list_ts,
    const float* __restrict__ list_w, const int* __restrict__ counts, const int* __restrict__ offs){
  int m0 = blockIdx.y<<7;
  if (m0 >= offs[8]) return;
  int e = 0;
  while (m0 >= offs[e+1]) e++;
  int base = offs[e], cnt = counts[e];
  if (m0 >= base + cnt) return;
  __shared__ __align__(16) _Float16 As[128*32], Bs[128*32];
  int tid = threadIdx.x, lane = tid&63, wvx = tid>>6;
  int wr = wvx>>1, wc = wvx&1, quad = lane>>4, lrow = lane&15;
  int n0 = blockIdx.x<<7;
  const _Float16* Be = dwt + (size_t)e*1024*2048 + (size_t)n0*2048;
  f32x4 acc[4][4] = {};
  for (int k0=0; k0<2048; k0+=32){
    #pragma unroll
    for (int it=0; it<2; it++){
      int c2 = it*256 + tid;
      int r = c2>>2, g = c2&3;
      gll16(&act[(size_t)(m0+r)*INTER_DIM + k0 + g*8], &As[(size_t)(it*256 + wvx*64)*8]);
      gll16(&Be[(size_t)r*2048 + k0 + g*8], &Bs[(size_t)(it*256 + wvx*64)*8]);
    }
    __syncthreads();
    h16x8 a[4], b[4];
    #pragma unroll
    for (int i=0;i<4;i++) a[i] = *(const h16x8*)&As[(wr*64 + i*16 + lrow)*32 + quad*8];
    #pragma unroll
    for (int j=0;j<4;j++) b[j] = *(const h16x8*)&Bs[(wc*64 + j*16 + lrow)*32 + quad*8];
    #pragma unroll
    for (int i=0;i<4;i++)
      #pragma unroll
      for (int j=0;j<4;j++)
        acc[i][j] = mfma16(a[i], b[j], acc[i][j]);
    __syncthreads();
  }
  #pragma unroll
  for (int i=0;i<4;i++)
    #pragma unroll
    for (int r=0;r<4;r++){
      int m = m0 + wr*64 + i*16 + quad*4 + r;
      if (m < base + cnt){
        int ts = list_ts[m];
        float wgt = list_w[m];
        #pragma unroll
        for (int j=0;j<4;j++){
          int col = n0 + wc*64 + j*16 + lrow;
          slotbuf[(size_t)ts*H_DIM + col] = (_Float16)(wgt * acc[i][j][r]);
        }
      }
    }
}

// ======== LEGACY PATH (ws too small for weight transposes) ========

__global__ __launch_bounds__(256) void k_gemm_gu(const _Float16* __restrict__ h2, const void* __restrict__ guw,
    _Float16* __restrict__ act, const int* __restrict__ list_ts,
    const int* __restrict__ counts, const int* __restrict__ offs, const int* __restrict__ df){
  const int is32 = *df;
  int m0 = blockIdx.y<<7;
  if (m0 >= offs[8]) return;
  int e = 0;
  while (m0 >= offs[e+1]) e++;
  int base = offs[e], cnt = counts[e];
  if (m0 >= base + cnt) return;
  __shared__ __align__(16) _Float16 As[128*32], Bg[64*40], Bu[64*40];
  __shared__ int rowtok[128];
  int tid = threadIdx.x;
  if (tid < 128){
    int mc = min(m0 + tid, base + cnt - 1);
    rowtok[tid] = list_ts[mc] >> 1;
  }
  __syncthreads();
  int lane = tid&63, wvx = tid>>6, wr = wvx>>1, wc = wvx&1, quad = lane>>4, lrow = lane&15;
  int n0 = blockIdx.x<<6;
  size_t ebase = (size_t)e*H_DIM*4096;
  f32x4 ag[4][2] = {}, au[4][2] = {};
  for (int k0=0; k0<1024; k0+=32){
    #pragma unroll
    for (int it=0; it<2; it++){
      int ch = it*256 + tid;
      int r = ch>>2, c = ch&3;
      *(i32x4*)&As[ch*8] = *(const i32x4*)&h2[(size_t)rowtok[r]*H_DIM + k0 + c*8];
    }
    {
      int k = tid>>3, g = tid&7;
      size_t rowb = ebase + (size_t)(k0+k)*4096;
      int ks = kslot_sw(k, g);
      _Float16 tg[8], tu[8];
      if (is32){
        const float* gf = (const float*)guw;
        f32x4 a0 = *(const f32x4*)&gf[rowb + n0 + g*8];
        f32x4 a1 = *(const f32x4*)&gf[rowb + n0 + g*8 + 4];
        f32x4 b0 = *(const f32x4*)&gf[rowb + 2048 + n0 + g*8];
        f32x4 b1 = *(const f32x4*)&gf[rowb + 2048 + n0 + g*8 + 4];
        #pragma unroll
        for (int i=0;i<4;i++){ tg[i]=(_Float16)a0[i]; tg[4+i]=(_Float16)a1[i];
                               tu[i]=(_Float16)b0[i]; tu[4+i]=(_Float16)b1[i]; }
      } else {
        const u16* gb = (const u16*)guw;
        u16x4 a0 = *(const u16x4*)&gb[rowb + n0 + g*8];
        u16x4 a1 = *(const u16x4*)&gb[rowb + n0 + g*8 + 4];
        u16x4 b0 = *(const u16x4*)&gb[rowb + 2048 + n0 + g*8];
        u16x4 b1 = *(const u16x4*)&gb[rowb + 2048 + n0 + g*8 + 4];
        #pragma unroll
        for (int i=0;i<4;i++){ tg[i]=(_Float16)bf2f(a0[i]); tg[4+i]=(_Float16)bf2f(a1[i]);
                               tu[i]=(_Float16)bf2f(b0[i]); tu[4+i]=(_Float16)bf2f(b1[i]); }
      }
      #pragma unroll
      for (int i=0;i<8;i++){
        int n = g*8 + i;
        Bg[n*40 + ks] = tg[i];
        Bu[n*40 + ks] = tu[i];
      }
    }
    __syncthreads();
    h16x8 a[4], bg[2], bu[2];
    #pragma unroll
    for (int i=0;i<4;i++) a[i] = *(const h16x8*)&As[(wr*64 + i*16 + lrow)*32 + quad*8];
    #pragma unroll
    for (int j=0;j<2;j++){
      int n = wc*32 + j*16 + lrow;
      int oct = (quad ^ ((n>>3)&3))*8;
      bg[j] = *(const h16x8*)&Bg[n*40 + oct];
      bu[j] = *(const h16x8*)&Bu[n*40 + oct];
    }
    #pragma unroll
    for (int i=0;i<4;i++)
      #pragma unroll
      for (int j=0;j<2;j++){
        ag[i][j] = mfma16(a[i], bg[j], ag[i][j]);
        au[i][j] = mfma16(a[i], bu[j], au[i][j]);
      }
    __syncthreads();
  }
  #pragma unroll
  for (int i=0;i<4;i++)
    #pragma unroll
    for (int j=0;j<2;j++)
      #pragma unroll
      for (int r=0;r<4;r++){
        int row = m0 + wr*64 + i*16 + quad*4 + r;
        int col = n0 + wc*32 + j*16 + lrow;
        float g = ag[i][j][r], u = au[i][j][r];
        float sv = g / (1.0f + __expf(-g));
        act[(size_t)row*INTER_DIM + col] = (_Float16)(sv * u);
      }
}

__global__ __launch_bounds__(256) void k_gemm_down(const _Float16* __restrict__ act, const void* __restrict__ dw,
    _Float16* __restrict__ slotbuf, const int* __restrict__ list_ts, const float* __restrict__ list_w,
    const int* __restrict__ counts, const int* __restrict__ offs, const int* __restrict__ df){
  const int is32 = *df;
  int m0 = blockIdx.y<<7;
  if (m0 >= offs[8]) return;
  int e = 0;
  while (m0 >= offs[e+1]) e++;
  int base = offs[e], cnt = counts[e];
  if (m0 >= base + cnt) return;
  __shared__ __align__(16) _Float16 As[128*32], Bs[128*40];
  int tid = threadIdx.x, lane = tid&63, wvx = tid>>6;
  int wr = wvx>>1, wc = wvx&1, quad = lane>>4, lrow = lane&15;
  int n0 = blockIdx.x<<7;
  size_t ebase = (size_t)e*INTER_DIM*H_DIM;
  f32x4 acc[4][4] = {};
  for (int k0=0; k0<2048; k0+=32){
    #pragma unroll
    for (int it=0; it<2; it++){
      int ch = it*256 + tid;
      int r = ch>>2, c = ch&3;
      *(i32x4*)&As[ch*8] = *(const i32x4*)&act[(size_t)(m0+r)*INTER_DIM + k0 + c*8];
    }
    {
      int k = tid>>3, g = tid&7;
      size_t rowb = ebase + (size_t)(k0+k)*H_DIM;
      int ks = kslot_sw(k, g);
      #pragma unroll
      for (int p=0;p<2;p++){
        _Float16 tb[8];
        if (is32){
          const float* bf = (const float*)dw;
          f32x4 a0 = *(const f32x4*)&bf[rowb + n0 + p*64 + g*8];
          f32x4 a1 = *(const f32x4*)&bf[rowb + n0 + p*64 + g*8 + 4];
          #pragma unroll
          for (int i=0;i<4;i++){ tb[i]=(_Float16)a0[i]; tb[4+i]=(_Float16)a1[i]; }
        } else {
          const u16* bb = (const u16*)dw;
          u16x4 a0 = *(const u16x4*)&bb[rowb + n0 + p*64 + g*8];
          u16x4 a1 = *(const u16x4*)&bb[rowb + n0 + p*64 + g*8 + 4];
          #pragma unroll
          for (int i=0;i<4;i++){ tb[i]=(_Float16)bf2f(a0[i]); tb[4+i]=(_Float16)bf2f(a1[i]); }
        }
        #pragma unroll
        for (int i=0;i<8;i++){
          int n = p*64 + g*8 + i;
          Bs[n*40 + ks] = tb[i];
        }
      }
    }
    __syncthreads();
    h16x8 a[4], b[4];
    #pragma unroll
    for (int i=0;i<4;i++) a[i] = *(const h16x8*)&As[(wr*64 + i*16 + lrow)*32 + quad*8];
    #pragma unroll
    for (int j=0;j<4;j++){
      int n = wc*64 + j*16 + lrow;
      b[j] = *(const h16x8*)&Bs[n*40 + ((quad ^ ((n>>3)&3))*8)];
    }
    #pragma unroll
    for (int i=0;i<4;i++)
      #pragma unroll
      for (int j=0;j<4;j++)
        acc[i][j] = mfma16(a[i], b[j], acc[i][j]);
    __syncthreads();
  }
  #pragma unroll
  for (int i=0;i<4;i++)
    #pragma unroll
    for (int r=0;r<4;r++){
      int m = m0 + wr*64 + i*16 + quad*4 + r;
      if (m < base + cnt){
        int ts = list_ts[m];
        float wgt = list_w[m];
        #pragma unroll
        for (int j=0;j<4;j++){
          int col = n0 + wc*64 + j*16 + lrow;
          slotbuf[(size_t)ts*H_DIM + col] = (_Float16)(wgt * acc[i][j][r]);
        }
      }
    }
}

// ---------------- final residual add -> dual-dtype out ----------------
__global__ __launch_bounds__(256) void k_final(const float* __restrict__ x1, const _Float16* __restrict__ slot,
                                               void* __restrict__ outv, const int* __restrict__ df){
  const int is32 = *df;
  int i4 = (blockIdx.x*256 + threadIdx.x)*4;
  int t = i4 >> 10, c = i4 & 1023;
  f32x4 a = *(const f32x4*)&x1[i4];
  h16x4 s0 = *(const h16x4*)&slot[(size_t)(t*2)*H_DIM + c];
  h16x4 s1 = *(const h16x4*)&slot[(size_t)(t*2+1)*H_DIM + c];
  if (is32){
    f32x4 o;
    #pragma unroll
    for (int m=0;m<4;m++) o[m] = a[m] + (float)s0[m] + (float)s1[m];
    *(f32x4*)&((float*)outv)[i4] = o;
  } else {
    u16x4 o;
    #pragma unroll
    for (int m=0;m<4;m++) o[m] = f2bf(a[m] + (float)s0[m] + (float)s1[m]);
    *(u16x4*)&((u16*)outv)[i4] = o;
  }
}

extern "C" void kernel_launch(void* const* d_in, const int* in_sizes, int n_in,
                              void* d_out, int out_size, void* d_ws, size_t ws_size,
                              hipStream_t stream){
  (void)in_sizes; (void)n_in; (void)out_size;
  const void* x    = d_in[0];
  const void* mask = d_in[1];
  const void* ln1  = d_in[2];
  const void* ln2  = d_in[3];
  const void* qkvw = d_in[4];
  const void* ow   = d_in[5];
  const void* rw   = d_in[6];
  const void* guw  = d_in[7];
  const void* dww  = d_in[8];

  char* ws = (char*)d_ws;
  size_t off = 0;
  auto alloc = [&](size_t b)->void*{ void* p = ws + off; off = (off + b + 255) & ~(size_t)255; return p; };
  int* meta            = (int*)alloc(32*sizeof(int));
  _Float16* qkv_wt     = (_Float16*)alloc((size_t)3072*1024*2);
  _Float16* o_wt       = (_Float16*)alloc((size_t)1024*1024*2);
  float* hbuf          = (float*)alloc((size_t)4096*1024*4);    // h / attn-out; later slotbuf
  float* qkvbuf        = (float*)alloc((size_t)4096*3072*4);    // qkv fp32; later h2+act
  float* x1            = (float*)alloc((size_t)4096*1024*4);
  int* list_ts         = (int*)alloc(MAXROWS*4);
  float* list_w        = (float*)alloc(MAXROWS*4);
  int* tok_e           = (int*)alloc((size_t)4096*2*4);
  float* tok_w         = (float*)alloc((size_t)4096*2*4);
  size_t base_end = off;                                         // ~92 MB
  _Float16* gu_wt      = (_Float16*)alloc((size_t)8*4096*1024*2); // 67 MB
  _Float16* down_wt    = (_Float16*)alloc((size_t)8*1024*2048*2); // 34 MB
  const int big = (ws_size >= off) ? 1 : 0;                       // need ~193 MB for hot path
  (void)base_end;

  int* counts = meta;
  int* offs   = meta + 8;
  int* fillpos= meta + 17;
  int* flag   = meta + 25;
  int* dflag  = meta + 26;
  _Float16* h2      = (_Float16*)qkvbuf;
  _Float16* act     = (_Float16*)((char*)qkvbuf + (size_t)4096*1024*2);
  _Float16* slotbuf = (_Float16*)hbuf;   // hbuf dead after o-proj

  hipMemsetAsync(meta, 0, 32*sizeof(int), stream);
  k_detect<<<dim3(1), dim3(64), 0, stream>>>((const uint32_t*)x, dflag);
  k_trans2<<<dim3(48, 16, 1), 256, 0, stream>>>(qkvw, qkv_wt, 1024, 3072, dflag);
  k_trans2<<<dim3(16, 16, 1), 256, 0, stream>>>(ow, o_wt, 1024, 1024, dflag);
  if (big){
    k_trans2<<<dim3(64, 16, 8), 256, 0, stream>>>(guw, gu_wt, 1024, 4096, dflag);
    k_trans2<<<dim3(16, 32, 8), 256, 0, stream>>>(dww, down_wt, 2048, 1024, dflag);
  }
  k_maskchk<<<dim3(1024), 256, 0, stream>>>(mask, flag, dflag);
  k_rms1<<<dim3(4096), 256, 0, stream>>>(x, ln1, hbuf, dflag);
  k_gemm_splitA<0><<<dim3(24, 32), 256, 0, stream>>>(hbuf, qkv_wt, qkvbuf, nullptr, 3072, 1024, dflag);
  k_attn<<<dim3(8, 64), 256, 0, stream>>>(qkvbuf, mask, flag, hbuf, dflag);
  k_gemm_splitA<1><<<dim3(8, 32), 256, 0, stream>>>(hbuf, o_wt, x1, x, 1024, 1024, dflag);
  k_rms2_router<<<dim3(4096), 256, 0, stream>>>(x1, ln2, rw, h2, tok_e, tok_w, counts, dflag);
  k_offsets<<<dim3(1), dim3(64), 0, stream>>>(counts, offs, fillpos);
  k_fill<<<dim3(16), 256, 0, stream>>>(tok_e, tok_w, fillpos, list_ts, list_w);
  if (big){
    k_gemm_gu_t<<<dim3(32, 72), 256, 0, stream>>>(h2, gu_wt, act, list_ts, counts, offs);
    k_gemm_down_t<<<dim3(8, 72), 256, 0, stream>>>(act, down_wt, slotbuf, list_ts, list_w, counts, offs);
  } else {
    k_gemm_gu<<<dim3(32, 72), 256, 0, stream>>>(h2, guw, act, list_ts, counts, offs, dflag);
    k_gemm_down<<<dim3(8, 72), 256, 0, stream>>>(act, dww, slotbuf, list_ts, list_w, counts, offs, dflag);
  }
  k_final<<<dim3(4096), 256, 0, stream>>>(x1, slotbuf, d_out, dflag);
}